// Round 1
// baseline (666.270 us; speedup 1.0000x reference)
//
#include <hip/hip_runtime.h>
#include <math.h>

#define HH 320
#define WW 320
#define HWP (HH * WW)     // pixels per batch image
#define KTOP 80

__device__ __forceinline__ float u2f(unsigned u) { return __uint_as_float(u); }

// ---- init small state: candidate counters + minmax slots -------------------
// mm layout: [0..B) prod_min, [B..2B) prod_max, [2B..3B) gauss_min, [3B..4B) gauss_max
__global__ void init_small_k(int* cand_cnt, unsigned* mm, int B_) {
    int t = threadIdx.x;
    if (t < B_) cand_cnt[t] = 0;
    if (t < 4 * B_) {
        int seg = t / B_;
        mm[t] = (seg == 0 || seg == 2) ? 0x7f800000u /* +inf */ : 0u;
    }
}

// ---- phase 1: row sums (9-tap, zero-padded SAME) for score and occupancy ---
__global__ void row_pool_k(const float* __restrict__ score,
                           float* __restrict__ rs_s, float* __restrict__ rs_o,
                           int total) {
    int gid = blockIdx.x * 256 + threadIdx.x;
    if (gid >= total) return;
    int x = gid % WW;
    int rowbase = gid - x;
    int x0 = x - 4 < 0 ? 0 : x - 4;
    int x1 = x + 4 > WW - 1 ? WW - 1 : x + 4;
    float ss = 0.f, so = 0.f;
    for (int xx = x0; xx <= x1; ++xx) {
        float v = score[rowbase + xx];
        ss += v;
        so += (v > 0.2f) ? 1.f : 0.f;
    }
    rs_s[gid] = ss;
    rs_o[gid] = so;
}

// ---- phase 2: col sums, prod = local_occ*local_mass, + per-batch min/max ---
__global__ void col_prod_k(const float* __restrict__ rs_s, const float* __restrict__ rs_o,
                           float* __restrict__ prod, unsigned* __restrict__ mm,
                           int B_, int total) {
    int gid = blockIdx.x * 256 + threadIdx.x;
    bool ok = gid < total;
    float pv = 0.f;
    if (ok) {
        int b = gid / HWP;
        int p = gid % HWP;
        int y = p / WW, x = p % WW;
        int y0 = y - 4 < 0 ? 0 : y - 4;
        int y1 = y + 4 > HH - 1 ? HH - 1 : y + 4;
        float ss = 0.f, so = 0.f;
        int base = b * HWP + x;
        for (int yy = y0; yy <= y1; ++yy) {
            ss += rs_s[base + yy * WW];
            so += rs_o[base + yy * WW];
        }
        pv = (so / 81.0f) * (ss / 81.0f);
        prod[gid] = pv;
    }
    // block min/max reduce (all values >= 0)
    __shared__ float smn[256], smx[256];
    smn[threadIdx.x] = ok ? pv : INFINITY;
    smx[threadIdx.x] = ok ? pv : 0.f;
    __syncthreads();
    for (int s = 128; s > 0; s >>= 1) {
        if (threadIdx.x < s) {
            smn[threadIdx.x] = fminf(smn[threadIdx.x], smn[threadIdx.x + s]);
            smx[threadIdx.x] = fmaxf(smx[threadIdx.x], smx[threadIdx.x + s]);
        }
        __syncthreads();
    }
    if (threadIdx.x == 0) {
        int b0 = (blockIdx.x * 256) / HWP;  // 102400 % 256 == 0 -> block never straddles batches
        atomicMin(&mm[b0], __float_as_uint(smn[0]));
        atomicMax(&mm[B_ + b0], __float_as_uint(smx[0]));
    }
}

// ---- phase 3: compact_score = score * norm01(prod) -------------------------
__global__ void compact_k(const float* __restrict__ score, const float* __restrict__ prod,
                          const unsigned* __restrict__ mm, float* __restrict__ cs,
                          int B_, int total) {
    int gid = blockIdx.x * 256 + threadIdx.x;
    if (gid >= total) return;
    int b = gid / HWP;
    float mn = u2f(mm[b]), mx = u2f(mm[B_ + b]);
    float c = (prod[gid] - mn) / (mx - mn + 1e-6f);
    cs[gid] = score[gid] * c;
}

// ---- phase 4: 5x5 NMS + candidate compaction --------------------------------
__global__ void nms_k(const float* __restrict__ cs, float* __restrict__ cand_val,
                      int* __restrict__ cand_idx, int* __restrict__ cand_cnt, int total) {
    int gid = blockIdx.x * 256 + threadIdx.x;
    if (gid >= total) return;
    int b = gid / HWP;
    int p = gid % HWP;
    int y = p / WW, x = p % WW;
    float v = cs[gid];
    if (v <= 0.f) return;  // maxima value must be > 0 to ever matter
    int y0 = y - 2 < 0 ? 0 : y - 2;
    int y1 = y + 2 > HH - 1 ? HH - 1 : y + 2;
    int x0 = x - 2 < 0 ? 0 : x - 2;
    int x1 = x + 2 > WW - 1 ? WW - 1 : x + 2;
    const float* c = cs + b * HWP;
    for (int yy = y0; yy <= y1; ++yy)
        for (int xx = x0; xx <= x1; ++xx)
            if (c[yy * WW + xx] > v) return;  // some neighbor strictly larger -> not a max
    int slot = atomicAdd(&cand_cnt[b], 1);
    cand_val[b * HWP + slot] = v;
    cand_idx[b * HWP + slot] = p;
}

// ---- phase 5: exact top-80 per batch + peak parameters ----------------------
__global__ void topk_k(float* __restrict__ cand_val, const int* __restrict__ cand_idx,
                       const int* __restrict__ cand_cnt, const float* __restrict__ depth,
                       float* __restrict__ peaks /* B*K*4 */) {
    int b = blockIdx.x;
    int tid = threadIdx.x;
    int n = cand_cnt[b];
    if (n > HWP) n = HWP;
    float* cv = cand_val + b * HWP;
    const int* ci = cand_idx + b * HWP;
    __shared__ float sv[256];
    __shared__ int sp[256];
    __shared__ float pk_v[KTOP];
    __shared__ int pk_i[KTOP];
    for (int k = 0; k < KTOP; ++k) {
        float bv = -1.f;
        int bp = -1;
        for (int i = tid; i < n; i += 256) {
            float v = cv[i];
            if (v > bv) { bv = v; bp = i; }
        }
        sv[tid] = bv; sp[tid] = bp;
        __syncthreads();
        for (int s = 128; s > 0; s >>= 1) {
            if (tid < s) {
                float vo = sv[tid + s]; int po = sp[tid + s];
                if (vo > sv[tid] || (vo == sv[tid] && po >= 0 && (sp[tid] < 0 || po < sp[tid]))) {
                    sv[tid] = vo; sp[tid] = po;
                }
            }
            __syncthreads();
        }
        if (tid == 0) {
            if (sv[0] > 0.f && sp[0] >= 0) {
                pk_v[k] = sv[0];
                pk_i[k] = ci[sp[0]];
                cv[sp[0]] = -2.f;  // suppress for next round
            } else {
                pk_v[k] = 0.f;
                pk_i[k] = -1;
            }
        }
        __syncthreads();
    }
    if (tid < KTOP) {
        float val = pk_v[tid];
        int idx = pk_i[tid];
        float xk = 0.f, yk = 0.f, inv = 0.f;
        if (val > 0.f && idx >= 0) {
            yk = (float)(idx / WW);
            xk = (float)(idx % WW);
            float z = depth[b * HWP + idx];
            z = fmaxf(z, 1e-3f);
            float r = 14.0f / z;
            r = fminf(fmaxf(r, 1.5f), 18.0f);
            float s2 = 0.6f * r;
            s2 = s2 * s2;
            inv = 1.0f / (2.0f * s2 + 1e-6f);
        }
        float* pk = peaks + (b * KTOP + tid) * 4;
        pk[0] = val; pk[1] = xk; pk[2] = yk; pk[3] = inv;
    }
}

// ---- phase 6: gaussian max map + per-batch min/max --------------------------
__global__ void gauss_k(const float* __restrict__ peaks, float* __restrict__ gauss,
                        unsigned* __restrict__ mm, int B_, int total) {
    int gid = blockIdx.x * 256 + threadIdx.x;
    int b0 = (blockIdx.x * 256) / HWP;
    __shared__ float4 spk[KTOP];
    if (threadIdx.x < KTOP)
        spk[threadIdx.x] = ((const float4*)peaks)[b0 * KTOP + threadIdx.x];
    __syncthreads();
    bool ok = gid < total;
    float m = 0.f;
    if (ok) {
        int p = gid % HWP;
        float fy = (float)(p / WW);
        float fx = (float)(p % WW);
        for (int k = 0; k < KTOP; ++k) {
            float4 pk = spk[k];
            if (pk.x <= m) break;  // peaks sorted desc: no later peak can raise m
            float dx = fx - pk.y;
            float dy = fy - pk.z;
            float t = -(dx * dx + dy * dy) * pk.w;
            float e = pk.x * __expf(t);
            m = fmaxf(m, e);
        }
        gauss[gid] = m;
    }
    __shared__ float smn[256], smx[256];
    smn[threadIdx.x] = ok ? m : INFINITY;
    smx[threadIdx.x] = ok ? m : 0.f;
    __syncthreads();
    for (int s = 128; s > 0; s >>= 1) {
        if (threadIdx.x < s) {
            smn[threadIdx.x] = fminf(smn[threadIdx.x], smn[threadIdx.x + s]);
            smx[threadIdx.x] = fmaxf(smx[threadIdx.x], smx[threadIdx.x + s]);
        }
        __syncthreads();
    }
    if (threadIdx.x == 0) {
        atomicMin(&mm[2 * B_ + b0], __float_as_uint(smn[0]));
        atomicMax(&mm[3 * B_ + b0], __float_as_uint(smx[0]));
    }
}

// ---- phase 7: final norm01 --------------------------------------------------
__global__ void norm_k(const float* __restrict__ gauss, const unsigned* __restrict__ mm,
                       float* __restrict__ out, int B_, int total) {
    int gid = blockIdx.x * 256 + threadIdx.x;
    if (gid >= total) return;
    int b = gid / HWP;
    float mn = u2f(mm[2 * B_ + b]), mx = u2f(mm[3 * B_ + b]);
    out[gid] = (gauss[gid] - mn) / (mx - mn + 1e-6f);
}

extern "C" void kernel_launch(void* const* d_in, const int* in_sizes, int n_in,
                              void* d_out, int out_size, void* d_ws, size_t ws_size,
                              hipStream_t stream) {
    const float* score = (const float*)d_in[0];
    const float* depth = (const float*)d_in[1];
    float* out = (float*)d_out;
    int total = in_sizes[0];       // B * H * W
    int B_ = total / HWP;          // 8

    // workspace layout (floats), with reuse:
    //  buf0: row-sum score -> cand_idx (int) -> gauss
    //  buf1: row-sum occ   -> compact_score
    //  buf2: prod          -> cand_val
    float* buf0 = (float*)d_ws;
    float* buf1 = buf0 + total;
    float* buf2 = buf1 + total;
    char* small = (char*)(buf2 + total);
    int* cand_cnt = (int*)small;
    unsigned* mm = (unsigned*)(small + B_ * sizeof(int));
    float* peaks = (float*)(small + B_ * sizeof(int) + 4 * B_ * sizeof(unsigned)); // 16B-aligned

    int nb = (total + 255) / 256;

    init_small_k<<<1, 256, 0, stream>>>(cand_cnt, mm, B_);
    row_pool_k<<<nb, 256, 0, stream>>>(score, buf0, buf1, total);
    col_prod_k<<<nb, 256, 0, stream>>>(buf0, buf1, buf2, mm, B_, total);
    compact_k<<<nb, 256, 0, stream>>>(score, buf2, mm, buf1, B_, total);          // buf1 = compact_score
    nms_k<<<nb, 256, 0, stream>>>(buf1, buf2, (int*)buf0, cand_cnt, total);       // buf2 = cand_val, buf0 = cand_idx
    topk_k<<<B_, 256, 0, stream>>>(buf2, (const int*)buf0, cand_cnt, depth, peaks);
    gauss_k<<<nb, 256, 0, stream>>>(peaks, buf0, mm, B_, total);                  // buf0 = gauss
    norm_k<<<nb, 256, 0, stream>>>(buf0, mm, out, B_, total);
}

// Round 2
// 277.514 us; speedup vs baseline: 2.4009x; 2.4009x over previous
//
#include <hip/hip_runtime.h>
#include <math.h>

#define HH 320
#define WW 320
#define HWP (HH * WW)     // pixels per batch image
#define KTOP 80
#define CNT_STRIDE 32     // pad per-batch counters to separate cache lines

__device__ __forceinline__ float u2f(unsigned u) { return __uint_as_float(u); }

// ---- init small state: candidate counters + minmax slots -------------------
// mm layout: [0..B) prod_min, [B..2B) prod_max, [2B..3B) gauss_min, [3B..4B) gauss_max
__global__ void init_small_k(int* cand_cnt, unsigned* mm, int B_) {
    int t = threadIdx.x;
    if (t < B_ * CNT_STRIDE) cand_cnt[t] = 0;
    if (t < 4 * B_) {
        int seg = t / B_;
        mm[t] = (seg == 0 || seg == 2) ? 0x7f800000u /* +inf */ : 0u;
    }
}

// ---- phase 1: row sums (9-tap, zero-padded SAME) for score and occupancy ---
__global__ void row_pool_k(const float* __restrict__ score,
                           float* __restrict__ rs_s, float* __restrict__ rs_o,
                           int total) {
    int gid = blockIdx.x * 256 + threadIdx.x;
    if (gid >= total) return;
    int x = gid % WW;
    int rowbase = gid - x;
    int x0 = x - 4 < 0 ? 0 : x - 4;
    int x1 = x + 4 > WW - 1 ? WW - 1 : x + 4;
    float ss = 0.f, so = 0.f;
    for (int xx = x0; xx <= x1; ++xx) {
        float v = score[rowbase + xx];
        ss += v;
        so += (v > 0.2f) ? 1.f : 0.f;
    }
    rs_s[gid] = ss;
    rs_o[gid] = so;
}

// ---- phase 2: col sums, prod = local_occ*local_mass, + per-batch min/max ---
__global__ void col_prod_k(const float* __restrict__ rs_s, const float* __restrict__ rs_o,
                           float* __restrict__ prod, unsigned* __restrict__ mm,
                           int B_, int total) {
    int gid = blockIdx.x * 256 + threadIdx.x;
    bool ok = gid < total;
    float pv = 0.f;
    if (ok) {
        int b = gid / HWP;
        int p = gid % HWP;
        int y = p / WW, x = p % WW;
        int y0 = y - 4 < 0 ? 0 : y - 4;
        int y1 = y + 4 > HH - 1 ? HH - 1 : y + 4;
        float ss = 0.f, so = 0.f;
        int base = b * HWP + x;
        for (int yy = y0; yy <= y1; ++yy) {
            ss += rs_s[base + yy * WW];
            so += rs_o[base + yy * WW];
        }
        pv = (so / 81.0f) * (ss / 81.0f);
        prod[gid] = pv;
    }
    __shared__ float smn[256], smx[256];
    smn[threadIdx.x] = ok ? pv : INFINITY;
    smx[threadIdx.x] = ok ? pv : 0.f;
    __syncthreads();
    for (int s = 128; s > 0; s >>= 1) {
        if (threadIdx.x < s) {
            smn[threadIdx.x] = fminf(smn[threadIdx.x], smn[threadIdx.x + s]);
            smx[threadIdx.x] = fmaxf(smx[threadIdx.x], smx[threadIdx.x + s]);
        }
        __syncthreads();
    }
    if (threadIdx.x == 0) {
        int b0 = (blockIdx.x * 256) / HWP;  // 102400 % 256 == 0 -> block never straddles batches
        atomicMin(&mm[b0], __float_as_uint(smn[0]));
        atomicMax(&mm[B_ + b0], __float_as_uint(smx[0]));
    }
}

// ---- phase 3: compact_score = score * norm01(prod) -------------------------
__global__ void compact_k(const float* __restrict__ score, const float* __restrict__ prod,
                          const unsigned* __restrict__ mm, float* __restrict__ cs,
                          int B_, int total) {
    int gid = blockIdx.x * 256 + threadIdx.x;
    if (gid >= total) return;
    int b = gid / HWP;
    float mn = u2f(mm[b]), mx = u2f(mm[B_ + b]);
    float c = (prod[gid] - mn) / (mx - mn + 1e-6f);
    cs[gid] = score[gid] * c;
}

// ---- phase 4: 5x5 NMS + block-aggregated candidate compaction ---------------
__global__ void nms_k(const float* __restrict__ cs, float* __restrict__ cand_val,
                      int* __restrict__ cand_idx, int* __restrict__ cand_cnt, int total) {
    int gid = blockIdx.x * 256 + threadIdx.x;
    int b = (blockIdx.x * 256) / HWP;   // block never straddles batches
    bool cand = false;
    float v = 0.f;
    int p = 0;
    if (gid < total) {
        p = gid % HWP;
        int y = p / WW, x = p % WW;
        v = cs[gid];
        if (v > 0.f) {
            int y0 = y - 2 < 0 ? 0 : y - 2;
            int y1 = y + 2 > HH - 1 ? HH - 1 : y + 2;
            int x0 = x - 2 < 0 ? 0 : x - 2;
            int x1 = x + 2 > WW - 1 ? WW - 1 : x + 2;
            const float* c = cs + b * HWP;
            cand = true;
            for (int yy = y0; yy <= y1 && cand; ++yy)
                for (int xx = x0; xx <= x1; ++xx)
                    if (c[yy * WW + xx] > v) { cand = false; break; }
        }
    }
    // one global atomic per block
    unsigned long long m = __ballot(cand);
    int lane = threadIdx.x & 63;
    int w = threadIdx.x >> 6;
    int pre = __popcll(m & ((1ULL << lane) - 1ULL));
    int wtot = __popcll(m);
    __shared__ int wbase[4];
    __shared__ int blockbase;
    if (lane == 0) wbase[w] = wtot;
    __syncthreads();
    if (threadIdx.x == 0) {
        int t0 = wbase[0], t1 = wbase[1], t2 = wbase[2], t3 = wbase[3];
        int tot = t0 + t1 + t2 + t3;
        wbase[0] = 0; wbase[1] = t0; wbase[2] = t0 + t1; wbase[3] = t0 + t1 + t2;
        blockbase = tot ? atomicAdd(&cand_cnt[b * CNT_STRIDE], tot) : 0;
    }
    __syncthreads();
    if (cand) {
        int slot = blockbase + wbase[w] + pre;
        cand_val[b * HWP + slot] = v;
        cand_idx[b * HWP + slot] = p;
    }
}

// ---- phase 5: radix-select top-80 per batch + peak parameters ---------------
__global__ void topk_k(const float* __restrict__ cand_val, const int* __restrict__ cand_idx,
                       const int* __restrict__ cand_cnt, const float* __restrict__ depth,
                       float* __restrict__ peaks /* B*K*4 */) {
    int b = blockIdx.x;
    int tid = threadIdx.x;  // 256 threads
    int n = cand_cnt[b * CNT_STRIDE];
    if (n > HWP) n = HWP;
    const float* cv = cand_val + b * HWP;
    const int* ci = cand_idx + b * HWP;

    __shared__ int hist[256];
    __shared__ unsigned s_prefix;
    __shared__ int s_kth;
    __shared__ float sel_v[KTOP];
    __shared__ int sel_i[KTOP];
    __shared__ int s_ng, s_nt;
    __shared__ int tie_i[512];
    __shared__ float pkv[KTOP];
    __shared__ int pki[KTOP];

    if (tid == 0) { s_prefix = 0; s_kth = KTOP; s_ng = 0; s_nt = 0; }
    if (tid < KTOP) { sel_v[tid] = 0.f; sel_i[tid] = HWP + tid; }  // zero-pad, distinct idx
    __syncthreads();

    if (n > KTOP) {
        // radix select (positive floats: uint order == float order): find 80th largest
        for (int shift = 24; shift >= 0; shift -= 8) {
            hist[tid] = 0;
            __syncthreads();
            unsigned pref = s_prefix;
            unsigned hmask = (shift == 24) ? 0u : (0xFFFFFFFFu << (shift + 8));
            for (int i = tid; i < n; i += 256) {
                unsigned u = __float_as_uint(cv[i]);
                if ((u & hmask) == (pref & hmask))
                    atomicAdd(&hist[(u >> shift) & 255], 1);
            }
            __syncthreads();
            if (tid == 0) {
                int kth = s_kth, cum = 0, bin = 0;
                for (int bi = 255; bi >= 0; --bi) {
                    int c = hist[bi];
                    if (cum + c >= kth) { bin = bi; break; }
                    cum += c;
                }
                s_prefix = pref | ((unsigned)bin << shift);
                s_kth = kth - cum;
            }
            __syncthreads();
        }
        unsigned T = s_prefix;
        int need_eq = s_kth;   // # of ==T entries to take (smallest flat indices first)
        for (int i = tid; i < n; i += 256) {
            unsigned u = __float_as_uint(cv[i]);
            if (u > T) {
                int s = atomicAdd(&s_ng, 1);
                if (s < KTOP) { sel_v[s] = cv[i]; sel_i[s] = ci[i]; }
            } else if (u == T) {
                int s = atomicAdd(&s_nt, 1);
                if (s < 512) tie_i[s] = ci[i];
            }
        }
        __syncthreads();
        int G = s_ng; if (G > KTOP) G = KTOP;
        int nt = s_nt; if (nt > 512) nt = 512;
        for (int t = tid; t < nt; t += 256) {
            int mine = tie_i[t];
            int rank = 0;
            for (int j = 0; j < nt; ++j) {
                int o = tie_i[j];
                if (o < mine || (o == mine && j < t)) rank++;
            }
            if (rank < need_eq && G + rank < KTOP) {
                sel_v[G + rank] = u2f(T);
                sel_i[G + rank] = mine;
            }
        }
        __syncthreads();
    } else {
        for (int i = tid; i < n; i += 256) { sel_v[i] = cv[i]; sel_i[i] = ci[i]; }
        __syncthreads();
    }

    // rank-sort the 80: descending by value, ascending by index (jax top_k order)
    if (tid < KTOP) {
        float v = sel_v[tid];
        int p = sel_i[tid];
        int rank = 0;
        for (int j = 0; j < KTOP; ++j) {
            float vj = sel_v[j]; int pj = sel_i[j];
            if (vj > v || (vj == v && pj < p)) rank++;
        }
        pkv[rank] = v;
        pki[rank] = p;
    }
    __syncthreads();
    if (tid < KTOP) {
        float val = pkv[tid];
        int idx = pki[tid];
        float xk = 0.f, yk = 0.f, inv = 0.f;
        if (val > 0.f && idx >= 0 && idx < HWP) {
            yk = (float)(idx / WW);
            xk = (float)(idx % WW);
            float z = fmaxf(depth[b * HWP + idx], 1e-3f);
            float r = fminf(fmaxf(14.0f / z, 1.5f), 18.0f);
            float s2 = 0.6f * r;
            s2 = s2 * s2;
            inv = 1.0f / (2.0f * s2 + 1e-6f);
        }
        float* pk = peaks + (b * KTOP + tid) * 4;
        pk[0] = val; pk[1] = xk; pk[2] = yk; pk[3] = inv;
    }
}

// ---- phase 6: gaussian max map + per-batch min/max --------------------------
__global__ void gauss_k(const float* __restrict__ peaks, float* __restrict__ gauss,
                        unsigned* __restrict__ mm, int B_, int total) {
    int gid = blockIdx.x * 256 + threadIdx.x;
    int b0 = (blockIdx.x * 256) / HWP;
    __shared__ float4 spk[KTOP];
    if (threadIdx.x < KTOP)
        spk[threadIdx.x] = ((const float4*)peaks)[b0 * KTOP + threadIdx.x];
    __syncthreads();
    bool ok = gid < total;
    float m = 0.f;
    if (ok) {
        int p = gid % HWP;
        float fy = (float)(p / WW);
        float fx = (float)(p % WW);
        for (int k = 0; k < KTOP; ++k) {
            float4 pk = spk[k];
            if (pk.x <= m) break;  // peaks sorted desc: no later peak can raise m
            float dx = fx - pk.y;
            float dy = fy - pk.z;
            float t = -(dx * dx + dy * dy) * pk.w;
            float e = pk.x * __expf(t);
            m = fmaxf(m, e);
        }
        gauss[gid] = m;
    }
    __shared__ float smn[256], smx[256];
    smn[threadIdx.x] = ok ? m : INFINITY;
    smx[threadIdx.x] = ok ? m : 0.f;
    __syncthreads();
    for (int s = 128; s > 0; s >>= 1) {
        if (threadIdx.x < s) {
            smn[threadIdx.x] = fminf(smn[threadIdx.x], smn[threadIdx.x + s]);
            smx[threadIdx.x] = fmaxf(smx[threadIdx.x], smx[threadIdx.x + s]);
        }
        __syncthreads();
    }
    if (threadIdx.x == 0) {
        atomicMin(&mm[2 * B_ + b0], __float_as_uint(smn[0]));
        atomicMax(&mm[3 * B_ + b0], __float_as_uint(smx[0]));
    }
}

// ---- phase 7: final norm01 --------------------------------------------------
__global__ void norm_k(const float* __restrict__ gauss, const unsigned* __restrict__ mm,
                       float* __restrict__ out, int B_, int total) {
    int gid = blockIdx.x * 256 + threadIdx.x;
    if (gid >= total) return;
    int b = gid / HWP;
    float mn = u2f(mm[2 * B_ + b]), mx = u2f(mm[3 * B_ + b]);
    out[gid] = (gauss[gid] - mn) / (mx - mn + 1e-6f);
}

extern "C" void kernel_launch(void* const* d_in, const int* in_sizes, int n_in,
                              void* d_out, int out_size, void* d_ws, size_t ws_size,
                              hipStream_t stream) {
    const float* score = (const float*)d_in[0];
    const float* depth = (const float*)d_in[1];
    float* out = (float*)d_out;
    int total = in_sizes[0];       // B * H * W
    int B_ = total / HWP;          // 8

    // workspace layout (floats), with reuse:
    //  buf0: row-sum score -> cand_idx (int) -> gauss
    //  buf1: row-sum occ   -> compact_score
    //  buf2: prod          -> cand_val
    float* buf0 = (float*)d_ws;
    float* buf1 = buf0 + total;
    float* buf2 = buf1 + total;
    char* small = (char*)(buf2 + total);
    int* cand_cnt = (int*)small;
    unsigned* mm = (unsigned*)(small + B_ * CNT_STRIDE * sizeof(int));
    float* peaks = (float*)(small + B_ * CNT_STRIDE * sizeof(int) + 4 * B_ * sizeof(unsigned));

    int nb = (total + 255) / 256;

    init_small_k<<<1, 256, 0, stream>>>(cand_cnt, mm, B_);
    row_pool_k<<<nb, 256, 0, stream>>>(score, buf0, buf1, total);
    col_prod_k<<<nb, 256, 0, stream>>>(buf0, buf1, buf2, mm, B_, total);
    compact_k<<<nb, 256, 0, stream>>>(score, buf2, mm, buf1, B_, total);          // buf1 = compact_score
    nms_k<<<nb, 256, 0, stream>>>(buf1, buf2, (int*)buf0, cand_cnt, total);       // buf2 = cand_val, buf0 = cand_idx
    topk_k<<<B_, 256, 0, stream>>>(buf2, (const int*)buf0, cand_cnt, depth, peaks);
    gauss_k<<<nb, 256, 0, stream>>>(peaks, buf0, mm, B_, total);                  // buf0 = gauss
    norm_k<<<nb, 256, 0, stream>>>(buf0, mm, out, B_, total);
}

// Round 3
// 222.675 us; speedup vs baseline: 2.9921x; 1.2463x over previous
//
#include <hip/hip_runtime.h>
#include <math.h>

#define HH 320
#define WW 320
#define HWP (HH * WW)     // pixels per batch image
#define KTOP 80
#define CNT_STRIDE 32     // pad per-batch counters to separate cache lines
#define CAP (HWP / 2)     // max candidates kept per batch (val+idx pack one HWP buffer)

__device__ __forceinline__ float u2f(unsigned u) { return __uint_as_float(u); }

// ---- init small state: candidate counters + minmax slots -------------------
// mm layout: [0..B) prod_min, [B..2B) prod_max, [2B..3B) gauss_min, [3B..4B) gauss_max
__global__ void init_small_k(int* cand_cnt, unsigned* mm, int B_) {
    int t = threadIdx.x;
    if (t < B_ * CNT_STRIDE) cand_cnt[t] = 0;
    if (t < 4 * B_) {
        int seg = t / B_;
        mm[t] = (seg == 0 || seg == 2) ? 0x7f800000u /* +inf */ : 0u;
    }
}

// ---- phase 1: row sums (9-tap, zero-padded SAME) for score and occupancy ---
__global__ void row_pool_k(const float* __restrict__ score,
                           float* __restrict__ rs_s, float* __restrict__ rs_o,
                           int total) {
    int gid = blockIdx.x * 256 + threadIdx.x;
    if (gid >= total) return;
    int x = gid % WW;
    int rowbase = gid - x;
    int x0 = x - 4 < 0 ? 0 : x - 4;
    int x1 = x + 4 > WW - 1 ? WW - 1 : x + 4;
    float ss = 0.f, so = 0.f;
    for (int xx = x0; xx <= x1; ++xx) {
        float v = score[rowbase + xx];
        ss += v;
        so += (v > 0.2f) ? 1.f : 0.f;
    }
    rs_s[gid] = ss;
    rs_o[gid] = so;
}

// ---- phase 2: col sums, prod = local_occ*local_mass, + per-batch min/max ---
__global__ void col_prod_k(const float* __restrict__ rs_s, const float* __restrict__ rs_o,
                           float* __restrict__ prod, unsigned* __restrict__ mm,
                           int B_, int total) {
    int gid = blockIdx.x * 256 + threadIdx.x;
    bool ok = gid < total;
    float pv = 0.f;
    if (ok) {
        int b = gid / HWP;
        int p = gid % HWP;
        int y = p / WW, x = p % WW;
        int y0 = y - 4 < 0 ? 0 : y - 4;
        int y1 = y + 4 > HH - 1 ? HH - 1 : y + 4;
        float ss = 0.f, so = 0.f;
        int base = b * HWP + x;
        for (int yy = y0; yy <= y1; ++yy) {
            ss += rs_s[base + yy * WW];
            so += rs_o[base + yy * WW];
        }
        pv = (so / 81.0f) * (ss / 81.0f);
        prod[gid] = pv;
    }
    __shared__ float smn[256], smx[256];
    smn[threadIdx.x] = ok ? pv : INFINITY;
    smx[threadIdx.x] = ok ? pv : 0.f;
    __syncthreads();
    for (int s = 128; s > 0; s >>= 1) {
        if (threadIdx.x < s) {
            smn[threadIdx.x] = fminf(smn[threadIdx.x], smn[threadIdx.x + s]);
            smx[threadIdx.x] = fmaxf(smx[threadIdx.x], smx[threadIdx.x + s]);
        }
        __syncthreads();
    }
    if (threadIdx.x == 0) {
        int b0 = (blockIdx.x * 256) / HWP;  // 102400 % 256 == 0 -> block never straddles batches
        atomicMin(&mm[b0], __float_as_uint(smn[0]));
        atomicMax(&mm[B_ + b0], __float_as_uint(smx[0]));
    }
}

// ---- phase 3: compact_score (fused with 5-tap row max), one block per row ---
__global__ void cs_rowmax_k(const float* __restrict__ score, const float* __restrict__ prod,
                            const unsigned* __restrict__ mm,
                            float* __restrict__ cs, float* __restrict__ rm, int B_) {
    int row = blockIdx.x;           // b*HH + y
    int b = row / HH;
    int x = threadIdx.x;            // 320 threads = one full row
    int gid = row * WW + x;
    __shared__ float s[WW];
    float mn = u2f(mm[b]), mx = u2f(mm[B_ + b]);
    float c = (prod[gid] - mn) / (mx - mn + 1e-6f);
    float v = score[gid] * c;
    s[x] = v;
    cs[gid] = v;
    __syncthreads();
    int x0 = x - 2 < 0 ? 0 : x - 2;
    int x1 = x + 2 > WW - 1 ? WW - 1 : x + 2;
    float m = s[x0];
    for (int xx = x0 + 1; xx <= x1; ++xx) m = fmaxf(m, s[xx]);
    rm[gid] = m;
}

// ---- phase 4: 5-tap col max of rm -> NMS keep + block-aggregated compaction -
__global__ void nms_colcand_k(const float* __restrict__ cs, const float* __restrict__ rm,
                              float* __restrict__ cand_base, int* __restrict__ cand_cnt,
                              int total) {
    int gid = blockIdx.x * 256 + threadIdx.x;
    int b = (blockIdx.x * 256) / HWP;   // block never straddles batches
    bool cand = false;
    float v = 0.f;
    int p = 0;
    if (gid < total) {
        p = gid % HWP;
        int y = p / WW, x = p % WW;
        v = cs[gid];
        const float* r = rm + b * HWP + x;
        int y0 = y - 2 < 0 ? 0 : y - 2;
        int y1 = y + 2 > HH - 1 ? HH - 1 : y + 2;
        float nm = r[y0 * WW];
        for (int yy = y0 + 1; yy <= y1; ++yy) nm = fmaxf(nm, r[yy * WW]);
        cand = (v > 0.f) && (v >= nm);   // v==nm since window includes self
    }
    unsigned long long mball = __ballot(cand);
    int lane = threadIdx.x & 63;
    int w = threadIdx.x >> 6;
    int pre = __popcll(mball & ((1ULL << lane) - 1ULL));
    int wtot = __popcll(mball);
    __shared__ int wbase[4];
    __shared__ int blockbase;
    if (lane == 0) wbase[w] = wtot;
    __syncthreads();
    if (threadIdx.x == 0) {
        int t0 = wbase[0], t1 = wbase[1], t2 = wbase[2], t3 = wbase[3];
        int tot = t0 + t1 + t2 + t3;
        wbase[0] = 0; wbase[1] = t0; wbase[2] = t0 + t1; wbase[3] = t0 + t1 + t2;
        blockbase = tot ? atomicAdd(&cand_cnt[b * CNT_STRIDE], tot) : 0;
    }
    __syncthreads();
    if (cand) {
        int slot = blockbase + wbase[w] + pre;
        if (slot < CAP) {
            float* cv = cand_base + b * HWP;
            int* ci = (int*)(cand_base + b * HWP + CAP);
            cv[slot] = v;
            ci[slot] = p;
        }
    }
}

// ---- phase 5: radix-select top-80 per batch + peak parameters ---------------
__global__ void topk_k(const float* __restrict__ cand_base, const int* __restrict__ cand_cnt,
                       const float* __restrict__ depth, float* __restrict__ peaks) {
    int b = blockIdx.x;
    int tid = threadIdx.x;  // 1024 threads
    int n = cand_cnt[b * CNT_STRIDE];
    if (n > CAP) n = CAP;
    const float* cv = cand_base + b * HWP;
    const int* ci = (const int*)(cand_base + b * HWP + CAP);

    __shared__ int hist[256];
    __shared__ int ss[256];
    __shared__ unsigned s_prefix;
    __shared__ int s_kth;
    __shared__ float sel_v[KTOP];
    __shared__ int sel_i[KTOP];
    __shared__ int s_ng, s_nt;
    __shared__ int tie_i[512];

    if (tid == 0) { s_prefix = 0; s_kth = KTOP; s_ng = 0; s_nt = 0; }
    if (tid < KTOP) { sel_v[tid] = 0.f; sel_i[tid] = -1; }
    __syncthreads();

    if (n > KTOP) {
        // radix select on float bits (positive floats: uint order == float order)
        for (int shift = 24; shift >= 0; shift -= 8) {
            if (tid < 256) hist[tid] = 0;
            __syncthreads();
            unsigned pref = s_prefix;
            unsigned hmask = (shift == 24) ? 0u : (0xFFFFFFFFu << (shift + 8));
            for (int i = tid; i < n; i += 1024) {
                unsigned u = __float_as_uint(cv[i]);
                if ((u & hmask) == (pref & hmask))
                    atomicAdd(&hist[(u >> shift) & 255], 1);
            }
            __syncthreads();
            // parallel suffix sums: ss[bi] = sum hist[bi..255]
            if (tid < 256) ss[tid] = hist[tid];
            __syncthreads();
            for (int off = 1; off < 256; off <<= 1) {
                int v2 = 0;
                if (tid < 256) { v2 = ss[tid]; if (tid + off < 256) v2 += ss[tid + off]; }
                __syncthreads();
                if (tid < 256) ss[tid] = v2;
                __syncthreads();
            }
            int kth = s_kth;
            __syncthreads();
            if (tid < 256) {
                int above = (tid == 255) ? 0 : ss[tid + 1];
                if (ss[tid] >= kth && above < kth) {
                    s_prefix = pref | ((unsigned)tid << shift);
                    s_kth = kth - above;
                }
            }
            __syncthreads();
        }
        unsigned T = s_prefix;
        int need_eq = s_kth;   // # of ==T entries to take (smallest pixel indices first)
        for (int i = tid; i < n; i += 1024) {
            unsigned u = __float_as_uint(cv[i]);
            if (u > T) {
                int s = atomicAdd(&s_ng, 1);
                if (s < KTOP) { sel_v[s] = cv[i]; sel_i[s] = ci[i]; }
            } else if (u == T) {
                int s = atomicAdd(&s_nt, 1);
                if (s < 512) tie_i[s] = ci[i];
            }
        }
        __syncthreads();
        int G = s_ng; if (G > KTOP) G = KTOP;
        int nt = s_nt; if (nt > 512) nt = 512;
        for (int t = tid; t < nt; t += 1024) {
            int mine = tie_i[t];
            int rank = 0;
            for (int j = 0; j < nt; ++j)
                if (tie_i[j] < mine) rank++;     // pixel indices are distinct
            if (rank < need_eq && G + rank < KTOP) {
                sel_v[G + rank] = u2f(T);
                sel_i[G + rank] = mine;
            }
        }
        __syncthreads();
    } else {
        for (int i = tid; i < n; i += 1024) { sel_v[i] = cv[i]; sel_i[i] = ci[i]; }
        __syncthreads();
    }

    // peak params (order irrelevant: gauss takes max over peaks)
    if (tid < KTOP) {
        float val = sel_v[tid];
        int idx = sel_i[tid];
        float xk = 0.f, yk = 0.f, wcoef = 0.f;
        if (val > 0.f && idx >= 0) {
            yk = (float)(idx / WW);
            xk = (float)(idx % WW);
            float z = fmaxf(depth[b * HWP + idx], 1e-3f);
            float r = fminf(fmaxf(14.0f / z, 1.5f), 18.0f);
            float s2 = 0.6f * r;
            s2 = s2 * s2;
            // fold log2(e) so gauss uses exp2f: val*exp(-d2/(2s2+eps)) = val*2^(d2*wcoef)
            wcoef = -1.4426950408889634f / (2.0f * s2 + 1e-6f);
        }
        float* pk = peaks + (b * KTOP + tid) * 4;
        pk[0] = val; pk[1] = xk; pk[2] = yk; pk[3] = wcoef;
    }
}

// ---- phase 6: gaussian max map (branchless) + per-batch min/max -------------
__global__ void gauss_k(const float* __restrict__ peaks, float* __restrict__ gauss,
                        unsigned* __restrict__ mm, int B_, int total) {
    int gid = blockIdx.x * 256 + threadIdx.x;
    int b0 = (blockIdx.x * 256) / HWP;
    __shared__ float4 spk[KTOP];
    if (threadIdx.x < KTOP)
        spk[threadIdx.x] = ((const float4*)peaks)[b0 * KTOP + threadIdx.x];
    __syncthreads();
    bool ok = gid < total;
    float m = 0.f;
    if (ok) {
        int p = gid % HWP;
        float fy = (float)(p / WW);
        float fx = (float)(p % WW);
#pragma unroll 8
        for (int k = 0; k < KTOP; ++k) {
            float4 pk = spk[k];
            float dx = fx - pk.y;
            float dy = fy - pk.z;
            m = fmaxf(m, pk.x * exp2f((dx * dx + dy * dy) * pk.w));
        }
        gauss[gid] = m;
    }
    __shared__ float smn[256], smx[256];
    smn[threadIdx.x] = ok ? m : INFINITY;
    smx[threadIdx.x] = ok ? m : 0.f;
    __syncthreads();
    for (int s = 128; s > 0; s >>= 1) {
        if (threadIdx.x < s) {
            smn[threadIdx.x] = fminf(smn[threadIdx.x], smn[threadIdx.x + s]);
            smx[threadIdx.x] = fmaxf(smx[threadIdx.x], smx[threadIdx.x + s]);
        }
        __syncthreads();
    }
    if (threadIdx.x == 0) {
        atomicMin(&mm[2 * B_ + b0], __float_as_uint(smn[0]));
        atomicMax(&mm[3 * B_ + b0], __float_as_uint(smx[0]));
    }
}

// ---- phase 7: final norm01 --------------------------------------------------
__global__ void norm_k(const float* __restrict__ gauss, const unsigned* __restrict__ mm,
                       float* __restrict__ out, int B_, int total) {
    int gid = blockIdx.x * 256 + threadIdx.x;
    if (gid >= total) return;
    int b = gid / HWP;
    float mn = u2f(mm[2 * B_ + b]), mx = u2f(mm[3 * B_ + b]);
    out[gid] = (gauss[gid] - mn) / (mx - mn + 1e-6f);
}

extern "C" void kernel_launch(void* const* d_in, const int* in_sizes, int n_in,
                              void* d_out, int out_size, void* d_ws, size_t ws_size,
                              hipStream_t stream) {
    const float* score = (const float*)d_in[0];
    const float* depth = (const float*)d_in[1];
    float* out = (float*)d_out;
    int total = in_sizes[0];       // B * H * W
    int B_ = total / HWP;          // 8

    // workspace (floats), with reuse:
    //  buf0: rs_s -> cs -> gauss
    //  buf1: rs_o -> rm
    //  buf2: prod -> {cand_val[0:CAP] | cand_idx[CAP:2*CAP]} per batch
    float* buf0 = (float*)d_ws;
    float* buf1 = buf0 + total;
    float* buf2 = buf1 + total;
    char* small = (char*)(buf2 + total);
    int* cand_cnt = (int*)small;
    unsigned* mm = (unsigned*)(small + B_ * CNT_STRIDE * sizeof(int));
    float* peaks = (float*)(small + B_ * CNT_STRIDE * sizeof(int) + 4 * B_ * sizeof(unsigned));

    int nb = (total + 255) / 256;

    init_small_k<<<1, 256, 0, stream>>>(cand_cnt, mm, B_);
    row_pool_k<<<nb, 256, 0, stream>>>(score, buf0, buf1, total);
    col_prod_k<<<nb, 256, 0, stream>>>(buf0, buf1, buf2, mm, B_, total);
    cs_rowmax_k<<<B_ * HH, WW, 0, stream>>>(score, buf2, mm, buf0, buf1, B_);   // buf0=cs, buf1=rm
    nms_colcand_k<<<nb, 256, 0, stream>>>(buf0, buf1, buf2, cand_cnt, total);   // buf2=cand pack
    topk_k<<<B_, 1024, 0, stream>>>(buf2, cand_cnt, depth, peaks);
    gauss_k<<<nb, 256, 0, stream>>>(peaks, buf0, mm, B_, total);                // buf0=gauss (cs dead)
    norm_k<<<nb, 256, 0, stream>>>(buf0, mm, out, B_, total);
}

// Round 4
// 154.461 us; speedup vs baseline: 4.3135x; 1.4416x over previous
//
#include <hip/hip_runtime.h>
#include <math.h>

#define HH 320
#define WW 320
#define HWP (HH * WW)     // pixels per batch image
#define KTOP 80
#define CNT_STRIDE 32     // pad per-batch counters to separate cache lines
#define CAP (HWP / 2)     // max candidates kept per batch (val+idx pack one HWP buffer)
#define TS 16             // gauss tile size
#define TPR (WW / TS)     // 20 tiles per row
#define TPI (TPR * (HH / TS))  // 400 tiles per image
#define LOG2E 1.4426950408889634f
#define NLOG2TAU 19.931568569324174f   // -log2(1e-6)

__device__ __forceinline__ float u2f(unsigned u) { return __uint_as_float(u); }

// ---- phase 1: row sums (9-tap, zero-padded SAME), 4 px/thread, + init ------
// mm layout: [0..B) prod_min, [B..2B) prod_max, [2B..3B) gauss_min, [3B..4B) gauss_max
__global__ void row_pool_k(const float* __restrict__ score,
                           float* __restrict__ rs_s, float* __restrict__ rs_o,
                           int total, int* __restrict__ cand_cnt,
                           unsigned* __restrict__ mm, int B_) {
    if (blockIdx.x == 0) {
        for (int t = threadIdx.x; t < B_ * CNT_STRIDE; t += blockDim.x) cand_cnt[t] = 0;
        for (int t = threadIdx.x; t < 4 * B_; t += blockDim.x) {
            int seg = t / B_;
            mm[t] = (seg == 0 || seg == 2) ? 0x7f800000u : 0u;
        }
    }
    int g4 = blockIdx.x * 256 + threadIdx.x;         // quad index
    if (g4 * 4 >= total) return;
    int rowq = g4 / (WW / 4);                        // b*HH + y
    int qi = g4 % (WW / 4);                          // quad within row
    const float4* row4 = (const float4*)(score + rowq * WW);
    float4 a = (qi > 0) ? row4[qi - 1] : make_float4(0.f, 0.f, 0.f, 0.f);
    float4 b = row4[qi];
    float4 c = (qi < WW / 4 - 1) ? row4[qi + 1] : make_float4(0.f, 0.f, 0.f, 0.f);
    float w0=a.x,w1=a.y,w2=a.z,w3=a.w,w4=b.x,w5=b.y,w6=b.z,w7=b.w,w8=c.x,w9=c.y,w10=c.z,w11=c.w;
    float t = w0+w1+w2+w3+w4+w5+w6+w7+w8;
    float o0=t; t += w9 - w0; float o1=t; t += w10 - w1; float o2=t; t += w11 - w2; float o3=t;
    float c0=(w0>0.2f)?1.f:0.f, c1=(w1>0.2f)?1.f:0.f, c2=(w2>0.2f)?1.f:0.f, c3=(w3>0.2f)?1.f:0.f;
    float c4=(w4>0.2f)?1.f:0.f, c5=(w5>0.2f)?1.f:0.f, c6=(w6>0.2f)?1.f:0.f, c7=(w7>0.2f)?1.f:0.f;
    float c8=(w8>0.2f)?1.f:0.f, c9=(w9>0.2f)?1.f:0.f, c10=(w10>0.2f)?1.f:0.f, c11=(w11>0.2f)?1.f:0.f;
    float u = c0+c1+c2+c3+c4+c5+c6+c7+c8;
    float p0=u; u += c9 - c0; float p1=u; u += c10 - c1; float p2=u; u += c11 - c2; float p3=u;
    ((float4*)rs_s)[g4] = make_float4(o0, o1, o2, o3);
    ((float4*)rs_o)[g4] = make_float4(p0, p1, p2, p3);
}

// ---- phase 2: col sums, prod = local_occ*local_mass, 4 px/thread, + minmax --
__global__ void col_prod_k(const float* __restrict__ rs_s, const float* __restrict__ rs_o,
                           float* __restrict__ prod, unsigned* __restrict__ mm,
                           int B_, int total) {
    int g4 = blockIdx.x * 256 + threadIdx.x;
    bool ok = (g4 * 4 < total);
    float tmn = INFINITY, tmx = 0.f;
    if (ok) {
        int gp = g4 * 4;
        int b = gp / HWP;
        int p = gp % HWP;
        int y = p / WW;
        int xq = (p % WW) / 4;
        int y0 = y - 4 < 0 ? 0 : y - 4;
        int y1 = y + 4 > HH - 1 ? HH - 1 : y + 4;
        const float4* S4 = (const float4*)(rs_s + b * HWP);
        const float4* O4 = (const float4*)(rs_o + b * HWP);
        float sx=0.f, sy=0.f, sz=0.f, sw=0.f, ox=0.f, oy=0.f, oz=0.f, ow=0.f;
        for (int yy = y0; yy <= y1; ++yy) {
            float4 s = S4[yy * (WW / 4) + xq];
            float4 o = O4[yy * (WW / 4) + xq];
            sx += s.x; sy += s.y; sz += s.z; sw += s.w;
            ox += o.x; oy += o.y; oz += o.z; ow += o.w;
        }
        const float inv81 = 1.0f / 81.0f;
        float px = (ox*inv81)*(sx*inv81), py = (oy*inv81)*(sy*inv81);
        float pz = (oz*inv81)*(sz*inv81), pw = (ow*inv81)*(sw*inv81);
        ((float4*)prod)[g4] = make_float4(px, py, pz, pw);
        tmn = fminf(fminf(px, py), fminf(pz, pw));
        tmx = fmaxf(fmaxf(px, py), fmaxf(pz, pw));
    }
    __shared__ float smn[256], smx[256];
    smn[threadIdx.x] = tmn;
    smx[threadIdx.x] = tmx;
    __syncthreads();
    for (int s = 128; s > 0; s >>= 1) {
        if (threadIdx.x < s) {
            smn[threadIdx.x] = fminf(smn[threadIdx.x], smn[threadIdx.x + s]);
            smx[threadIdx.x] = fmaxf(smx[threadIdx.x], smx[threadIdx.x + s]);
        }
        __syncthreads();
    }
    if (threadIdx.x == 0) {
        int b0 = (blockIdx.x * 1024) / HWP;   // 1024 px/block divides HWP -> no straddle
        atomicMin(&mm[b0], __float_as_uint(smn[0]));
        atomicMax(&mm[B_ + b0], __float_as_uint(smx[0]));
    }
}

// ---- phase 3: compact_score (fused with 5-tap row max), one block per row ---
__global__ void cs_rowmax_k(const float* __restrict__ score, const float* __restrict__ prod,
                            const unsigned* __restrict__ mm,
                            float* __restrict__ cs, float* __restrict__ rm, int B_) {
    int row = blockIdx.x;           // b*HH + y
    int b = row / HH;
    int x = threadIdx.x;            // 320 threads = one full row
    int gid = row * WW + x;
    __shared__ float s[WW];
    float mn = u2f(mm[b]), mx = u2f(mm[B_ + b]);
    float inv = 1.0f / (mx - mn + 1e-6f);
    float v = score[gid] * ((prod[gid] - mn) * inv);
    s[x] = v;
    cs[gid] = v;
    __syncthreads();
    int x0 = x - 2 < 0 ? 0 : x - 2;
    int x1 = x + 2 > WW - 1 ? WW - 1 : x + 2;
    float m = s[x0];
    for (int xx = x0 + 1; xx <= x1; ++xx) m = fmaxf(m, s[xx]);
    rm[gid] = m;
}

// ---- phase 4: 5-tap col max of rm -> NMS keep + block-aggregated compaction -
__global__ void nms_colcand_k(const float* __restrict__ cs, const float* __restrict__ rm,
                              float* __restrict__ cand_base, int* __restrict__ cand_cnt,
                              int total) {
    int gid = blockIdx.x * 256 + threadIdx.x;
    int b = (blockIdx.x * 256) / HWP;   // block never straddles batches
    bool cand = false;
    float v = 0.f;
    int p = 0;
    if (gid < total) {
        p = gid % HWP;
        int y = p / WW, x = p % WW;
        v = cs[gid];
        const float* r = rm + b * HWP + x;
        int y0 = y - 2 < 0 ? 0 : y - 2;
        int y1 = y + 2 > HH - 1 ? HH - 1 : y + 2;
        float nm = r[y0 * WW];
        for (int yy = y0 + 1; yy <= y1; ++yy) nm = fmaxf(nm, r[yy * WW]);
        cand = (v > 0.f) && (v >= nm);   // v==nm since window includes self
    }
    unsigned long long mball = __ballot(cand);
    int lane = threadIdx.x & 63;
    int w = threadIdx.x >> 6;
    int pre = __popcll(mball & ((1ULL << lane) - 1ULL));
    int wtot = __popcll(mball);
    __shared__ int wbase[4];
    __shared__ int blockbase;
    if (lane == 0) wbase[w] = wtot;
    __syncthreads();
    if (threadIdx.x == 0) {
        int t0 = wbase[0], t1 = wbase[1], t2 = wbase[2], t3 = wbase[3];
        int tot = t0 + t1 + t2 + t3;
        wbase[0] = 0; wbase[1] = t0; wbase[2] = t0 + t1; wbase[3] = t0 + t1 + t2;
        blockbase = tot ? atomicAdd(&cand_cnt[b * CNT_STRIDE], tot) : 0;
    }
    __syncthreads();
    if (cand) {
        int slot = blockbase + wbase[w] + pre;
        if (slot < CAP) {
            float* cv = cand_base + b * HWP;
            int* ci = (int*)(cand_base + b * HWP + CAP);
            cv[slot] = v;
            ci[slot] = p;
        }
    }
}

// ---- phase 5: radix-select top-80 + peak params + tile binning --------------
__global__ void topk_bin_k(const float* __restrict__ cand_base, const int* __restrict__ cand_cnt,
                           const float* __restrict__ depth, float4* __restrict__ pk4g,
                           int* __restrict__ tcnt, int* __restrict__ tlist) {
    int b = blockIdx.x;
    int tid = threadIdx.x;  // 512 threads
    int n = cand_cnt[b * CNT_STRIDE];
    if (n > CAP) n = CAP;
    const float* cv = cand_base + b * HWP;
    const int* ci = (const int*)(cand_base + b * HWP + CAP);

    __shared__ int hist[256];
    __shared__ unsigned s_prefix;
    __shared__ int s_kth;
    __shared__ float sel_v[KTOP];
    __shared__ int sel_i[KTOP];
    __shared__ int s_ng, s_nt;
    __shared__ int tie_i[512];
    __shared__ float4 spk[KTOP];
    __shared__ float scut[KTOP];

    if (tid == 0) { s_prefix = 0; s_kth = KTOP; s_ng = 0; s_nt = 0; }
    if (tid < KTOP) { sel_v[tid] = 0.f; sel_i[tid] = -1; }
    __syncthreads();

    if (n > KTOP) {
        // radix select on float bits (positive floats: uint order == float order)
        for (int shift = 24; shift >= 0; shift -= 8) {
            if (tid < 256) hist[tid] = 0;
            __syncthreads();
            unsigned pref = s_prefix;
            unsigned hmask = (shift == 24) ? 0u : (0xFFFFFFFFu << (shift + 8));
            for (int i = tid; i < n; i += 512) {
                unsigned u = __float_as_uint(cv[i]);
                if ((u & hmask) == (pref & hmask))
                    atomicAdd(&hist[(u >> shift) & 255], 1);
            }
            __syncthreads();
            // single-wave suffix-scan of 256 bins (lane L owns bins 4L..4L+3)
            if (tid < 64) {
                int h0 = hist[tid*4+0], h1 = hist[tid*4+1], h2 = hist[tid*4+2], h3 = hist[tid*4+3];
                int ls3 = h3, ls2 = h2 + ls3, ls1 = h1 + ls2, ls0 = h0 + ls1;
                int sum = ls0;
                for (int off = 1; off < 64; off <<= 1) {
                    int vv = __shfl_down(sum, off, 64);
                    if (tid + off < 64) sum += vv;
                }
                int excl = sum - ls0;          // sum over lanes > L
                int kth = s_kth;
                int SS0 = ls0 + excl, SS1 = ls1 + excl, SS2 = ls2 + excl, SS3 = ls3 + excl, SS4 = excl;
                unsigned pr = s_prefix;
                int bin = -1, rem = 0;
                if (SS0 >= kth && SS1 < kth) { bin = tid*4+0; rem = kth - SS1; }
                else if (SS1 >= kth && SS2 < kth) { bin = tid*4+1; rem = kth - SS2; }
                else if (SS2 >= kth && SS3 < kth) { bin = tid*4+2; rem = kth - SS3; }
                else if (SS3 >= kth && SS4 < kth) { bin = tid*4+3; rem = kth - SS4; }
                if (bin >= 0) { s_prefix = pr | ((unsigned)bin << shift); s_kth = rem; }
            }
            __syncthreads();
        }
        unsigned T = s_prefix;
        int need_eq = s_kth;   // # of ==T entries to take (smallest pixel indices first)
        for (int i = tid; i < n; i += 512) {
            unsigned u = __float_as_uint(cv[i]);
            if (u > T) {
                int s = atomicAdd(&s_ng, 1);
                if (s < KTOP) { sel_v[s] = cv[i]; sel_i[s] = ci[i]; }
            } else if (u == T) {
                int s = atomicAdd(&s_nt, 1);
                if (s < 512) tie_i[s] = ci[i];
            }
        }
        __syncthreads();
        int G = s_ng; if (G > KTOP) G = KTOP;
        int nt = s_nt; if (nt > 512) nt = 512;
        for (int t = tid; t < nt; t += 512) {
            int mine = tie_i[t];
            int rank = 0;
            for (int j = 0; j < nt; ++j)
                if (tie_i[j] < mine) rank++;     // pixel indices are distinct
            if (rank < need_eq && G + rank < KTOP) {
                sel_v[G + rank] = u2f(T);
                sel_i[G + rank] = mine;
            }
        }
        __syncthreads();
    } else {
        for (int i = tid; i < n; i += 512) { sel_v[i] = cv[i]; sel_i[i] = ci[i]; }
        __syncthreads();
    }

    // peak params: (lv=log2 val, x, y, w) + cutoff d2; order irrelevant (max)
    if (tid < KTOP) {
        float val = sel_v[tid];
        int idx = sel_i[tid];
        float xk = 0.f, yk = 0.f, wv = 0.f, lv = -INFINITY, cut = -1.f;
        if (val > 0.f && idx >= 0) {
            yk = (float)(idx / WW);
            xk = (float)(idx % WW);
            float z = fmaxf(depth[b * HWP + idx], 1e-3f);
            float r = fminf(fmaxf(14.0f / z, 1.5f), 18.0f);
            float s2 = 0.6f * r;
            s2 = s2 * s2;
            wv = -LOG2E / (2.0f * s2 + 1e-6f);
            lv = log2f(val);
            cut = (lv + NLOG2TAU) / (-wv);   // contribution >= 1e-6 iff d2 <= cut
        }
        float4 pk = make_float4(lv, xk, yk, wv);
        spk[tid] = pk;
        scut[tid] = cut;
        pk4g[b * KTOP + tid] = pk;
    }
    __syncthreads();

    // tile binning: tile t gets peak k if min dist(rect, peak)^2 <= cut
    for (int t = tid; t < TPI; t += 512) {
        int ty = t / TPR, tx = t % TPR;
        float x0 = (float)(tx * TS), x1 = x0 + (TS - 1);
        float y0 = (float)(ty * TS), y1 = y0 + (TS - 1);
        int c = 0;
        int base = (b * TPI + t) * KTOP;
        for (int k = 0; k < KTOP; ++k) {
            float4 pk = spk[k];
            float cx = fminf(fmaxf(pk.y, x0), x1);
            float cy = fminf(fmaxf(pk.z, y0), y1);
            float dx = pk.y - cx, dy = pk.z - cy;
            float d2 = dx * dx + dy * dy;
            if (d2 <= scut[k]) tlist[base + c++] = k;
        }
        tcnt[b * TPI + t] = c;
    }
}

// ---- phase 6: gaussian max map over tile's peak list + per-batch min/max ----
__global__ void gauss_tiled_k(const float4* __restrict__ pk4g, const int* __restrict__ tcnt,
                              const int* __restrict__ tlist, float* __restrict__ gauss,
                              unsigned* __restrict__ mm, int B_) {
    int tb = blockIdx.x;
    int b = tb / TPI;
    int t = tb % TPI;
    int ty = t / TPR, tx = t % TPR;
    int ly = threadIdx.x / TS, lx = threadIdx.x % TS;
    int y = ty * TS + ly, x = tx * TS + lx;
    __shared__ float4 spk[KTOP];
    int cnt = tcnt[tb];
    if (threadIdx.x < cnt)
        spk[threadIdx.x] = pk4g[b * KTOP + tlist[tb * KTOP + threadIdx.x]];
    __syncthreads();
    float fx = (float)x, fy = (float)y;
    float m = 0.f;
    for (int i = 0; i < cnt; ++i) {
        float4 pk = spk[i];
        float dx = fx - pk.y, dy = fy - pk.z;
        float d2 = fmaf(dx, dx, dy * dy);
        m = fmaxf(m, __builtin_amdgcn_exp2f(fmaf(d2, pk.w, pk.x)));
    }
    gauss[b * HWP + y * WW + x] = m;
    __shared__ float smn[256], smx[256];
    smn[threadIdx.x] = m;
    smx[threadIdx.x] = m;
    __syncthreads();
    for (int s = 128; s > 0; s >>= 1) {
        if (threadIdx.x < s) {
            smn[threadIdx.x] = fminf(smn[threadIdx.x], smn[threadIdx.x + s]);
            smx[threadIdx.x] = fmaxf(smx[threadIdx.x], smx[threadIdx.x + s]);
        }
        __syncthreads();
    }
    if (threadIdx.x == 0) {
        atomicMin(&mm[2 * B_ + b], __float_as_uint(smn[0]));
        atomicMax(&mm[3 * B_ + b], __float_as_uint(smx[0]));
    }
}

// ---- phase 7: final norm01, 4 px/thread -------------------------------------
__global__ void norm_k(const float* __restrict__ gauss, const unsigned* __restrict__ mm,
                       float* __restrict__ out, int B_, int total) {
    int g4 = blockIdx.x * 256 + threadIdx.x;
    if (g4 * 4 >= total) return;
    int b = (g4 * 4) / HWP;
    float mn = u2f(mm[2 * B_ + b]), mx = u2f(mm[3 * B_ + b]);
    float inv = 1.0f / (mx - mn + 1e-6f);
    float4 g = ((const float4*)gauss)[g4];
    ((float4*)out)[g4] = make_float4((g.x - mn) * inv, (g.y - mn) * inv,
                                     (g.z - mn) * inv, (g.w - mn) * inv);
}

extern "C" void kernel_launch(void* const* d_in, const int* in_sizes, int n_in,
                              void* d_out, int out_size, void* d_ws, size_t ws_size,
                              hipStream_t stream) {
    const float* score = (const float*)d_in[0];
    const float* depth = (const float*)d_in[1];
    float* out = (float*)d_out;
    int total = in_sizes[0];       // B * H * W
    int B_ = total / HWP;          // 8

    // workspace (floats), with reuse:
    //  buf0: rs_s -> cs -> gauss
    //  buf1: rs_o -> rm -> {tcnt[B*TPI] | tlist[B*TPI*KTOP]}
    //  buf2: prod -> {cand_val[0:CAP] | cand_idx[CAP:2*CAP]} per batch
    float* buf0 = (float*)d_ws;
    float* buf1 = buf0 + total;
    float* buf2 = buf1 + total;
    char* small = (char*)(buf2 + total);
    int* cand_cnt = (int*)small;
    unsigned* mm = (unsigned*)(small + B_ * CNT_STRIDE * sizeof(int));
    float4* pk4 = (float4*)(small + B_ * CNT_STRIDE * sizeof(int) + 4 * B_ * sizeof(unsigned));
    int* tcnt = (int*)buf1;
    int* tlist = tcnt + B_ * TPI;

    int nb4 = (total / 4 + 255) / 256;     // 800
    int nb = (total + 255) / 256;          // 3200

    row_pool_k<<<nb4, 256, 0, stream>>>(score, buf0, buf1, total, cand_cnt, mm, B_);
    col_prod_k<<<nb4, 256, 0, stream>>>(buf0, buf1, buf2, mm, B_, total);
    cs_rowmax_k<<<B_ * HH, WW, 0, stream>>>(score, buf2, mm, buf0, buf1, B_);   // buf0=cs, buf1=rm
    nms_colcand_k<<<nb, 256, 0, stream>>>(buf0, buf1, buf2, cand_cnt, total);   // buf2=cand pack
    topk_bin_k<<<B_, 512, 0, stream>>>(buf2, cand_cnt, depth, pk4, tcnt, tlist);
    gauss_tiled_k<<<B_ * TPI, 256, 0, stream>>>(pk4, tcnt, tlist, buf0, mm, B_); // buf0=gauss
    norm_k<<<nb4, 256, 0, stream>>>(buf0, mm, out, B_, total);
}

// Round 5
// 61.545 us; speedup vs baseline: 10.8257x; 2.5097x over previous
//
#include <hip/hip_runtime.h>
#include <math.h>

#define HH 320
#define WW 320
#define HWP (HH * WW)     // pixels per batch image
#define KTOP 80
#define CNT_STRIDE 64     // pad per-batch counters to separate 256B lines
#define CAP (HWP / 2)     // max candidates kept per batch (val+idx pack one HWP buffer)
#define TS 16             // gauss tile size
#define TPR (WW / TS)     // 20 tiles per row
#define TPI (TPR * (HH / TS))  // 400 tiles per image
#define BLK4 (HWP / 1024) // 100 quad-blocks per image
#define LOG2E 1.4426950408889634f
#define NLOG2TAU 19.931568569324174f   // -log2(1e-6)

__device__ __forceinline__ void wave_minmax(float& mn, float& mx) {
    for (int off = 32; off > 0; off >>= 1) {
        mn = fminf(mn, __shfl_xor(mn, off, 64));
        mx = fmaxf(mx, __shfl_xor(mx, off, 64));
    }
}

// ---- phase 1: row sums (9-tap, zero-padded SAME), 4 px/thread, + init ------
__global__ void row_pool_k(const float* __restrict__ score,
                           float* __restrict__ rs_s, float* __restrict__ rs_o,
                           int total, int* __restrict__ cand_cnt, int B_) {
    if (blockIdx.x == 0) {
        for (int t = threadIdx.x; t < B_ * CNT_STRIDE; t += blockDim.x) cand_cnt[t] = 0;
    }
    int g4 = blockIdx.x * 256 + threadIdx.x;         // quad index
    if (g4 * 4 >= total) return;
    int rowq = g4 / (WW / 4);                        // b*HH + y
    int qi = g4 % (WW / 4);                          // quad within row
    const float4* row4 = (const float4*)(score + rowq * WW);
    float4 a = (qi > 0) ? row4[qi - 1] : make_float4(0.f, 0.f, 0.f, 0.f);
    float4 b = row4[qi];
    float4 c = (qi < WW / 4 - 1) ? row4[qi + 1] : make_float4(0.f, 0.f, 0.f, 0.f);
    float w0=a.x,w1=a.y,w2=a.z,w3=a.w,w4=b.x,w5=b.y,w6=b.z,w7=b.w,w8=c.x,w9=c.y,w10=c.z,w11=c.w;
    float t = w0+w1+w2+w3+w4+w5+w6+w7+w8;
    float o0=t; t += w9 - w0; float o1=t; t += w10 - w1; float o2=t; t += w11 - w2; float o3=t;
    float c0=(w0>0.2f)?1.f:0.f, c1=(w1>0.2f)?1.f:0.f, c2=(w2>0.2f)?1.f:0.f, c3=(w3>0.2f)?1.f:0.f;
    float c4=(w4>0.2f)?1.f:0.f, c5=(w5>0.2f)?1.f:0.f, c6=(w6>0.2f)?1.f:0.f, c7=(w7>0.2f)?1.f:0.f;
    float c8=(w8>0.2f)?1.f:0.f, c9=(w9>0.2f)?1.f:0.f, c10=(w10>0.2f)?1.f:0.f, c11=(w11>0.2f)?1.f:0.f;
    float u = c0+c1+c2+c3+c4+c5+c6+c7+c8;
    float p0=u; u += c9 - c0; float p1=u; u += c10 - c1; float p2=u; u += c11 - c2; float p3=u;
    ((float4*)rs_s)[g4] = make_float4(o0, o1, o2, o3);
    ((float4*)rs_o)[g4] = make_float4(p0, p1, p2, p3);
}

// ---- phase 2: col sums, prod, 4 px/thread; per-block minmax -> scratch ------
__global__ void col_prod_k(const float* __restrict__ rs_s, const float* __restrict__ rs_o,
                           float* __restrict__ prod, float2* __restrict__ pmm, int total) {
    int g4 = blockIdx.x * 256 + threadIdx.x;
    float tmn = INFINITY, tmx = 0.f;
    if (g4 * 4 < total) {
        int gp = g4 * 4;
        int b = gp / HWP;
        int p = gp % HWP;
        int y = p / WW;
        int xq = (p % WW) / 4;
        int y0 = y - 4 < 0 ? 0 : y - 4;
        int y1 = y + 4 > HH - 1 ? HH - 1 : y + 4;
        const float4* S4 = (const float4*)(rs_s + b * HWP);
        const float4* O4 = (const float4*)(rs_o + b * HWP);
        float sx=0.f, sy=0.f, sz=0.f, sw=0.f, ox=0.f, oy=0.f, oz=0.f, ow=0.f;
        for (int yy = y0; yy <= y1; ++yy) {
            float4 s = S4[yy * (WW / 4) + xq];
            float4 o = O4[yy * (WW / 4) + xq];
            sx += s.x; sy += s.y; sz += s.z; sw += s.w;
            ox += o.x; oy += o.y; oz += o.z; ow += o.w;
        }
        const float inv81 = 1.0f / 81.0f;
        float px = (ox*inv81)*(sx*inv81), py = (oy*inv81)*(sy*inv81);
        float pz = (oz*inv81)*(sz*inv81), pw = (ow*inv81)*(sw*inv81);
        ((float4*)prod)[g4] = make_float4(px, py, pz, pw);
        tmn = fminf(fminf(px, py), fminf(pz, pw));
        tmx = fmaxf(fmaxf(px, py), fmaxf(pz, pw));
    }
    wave_minmax(tmn, tmx);
    __shared__ float wmn[4], wmx[4];
    int w = threadIdx.x >> 6;
    if ((threadIdx.x & 63) == 0) { wmn[w] = tmn; wmx[w] = tmx; }
    __syncthreads();
    if (threadIdx.x == 0) {
        pmm[blockIdx.x] = make_float2(fminf(fminf(wmn[0], wmn[1]), fminf(wmn[2], wmn[3])),
                                      fmaxf(fmaxf(wmx[0], wmx[1]), fmaxf(wmx[2], wmx[3])));
    }
}

// ---- phase 3: compact_score + 5-tap row max; prod-minmax reduced in-block ---
__global__ void cs_rowmax_k(const float* __restrict__ score, const float* __restrict__ prod,
                            const float2* __restrict__ pmm,
                            float* __restrict__ cs, float* __restrict__ rm) {
    int row = blockIdx.x;           // b*HH + y
    int b = row / HH;
    int x = threadIdx.x;            // 320 threads = one full row (5 waves)
    int gid = row * WW + x;
    // reduce this batch's 100 per-block minmax pairs (redundant per block, cheap)
    float tmn = INFINITY, tmx = 0.f;
    if (x < BLK4) { float2 e = pmm[b * BLK4 + x]; tmn = e.x; tmx = e.y; }
    wave_minmax(tmn, tmx);
    __shared__ float wmn[5], wmx[5];
    __shared__ float s[WW];
    __shared__ float bmn, binv;
    int w = x >> 6;
    if ((x & 63) == 0) { wmn[w] = tmn; wmx[w] = tmx; }
    __syncthreads();
    if (x == 0) {
        float mn = fminf(fminf(wmn[0], wmn[1]), wmn[2]);  // entries only in waves 0-1, rest identity
        float mx = fmaxf(fmaxf(wmx[0], wmx[1]), wmx[2]);
        mn = fminf(mn, fminf(wmn[3], wmn[4]));
        mx = fmaxf(mx, fmaxf(wmx[3], wmx[4]));
        bmn = mn;
        binv = 1.0f / (mx - mn + 1e-6f);
    }
    __syncthreads();
    float v = score[gid] * ((prod[gid] - bmn) * binv);
    s[x] = v;
    cs[gid] = v;
    __syncthreads();
    int x0 = x - 2 < 0 ? 0 : x - 2;
    int x1 = x + 2 > WW - 1 ? WW - 1 : x + 2;
    float m = s[x0];
    for (int xx = x0 + 1; xx <= x1; ++xx) m = fmaxf(m, s[xx]);
    rm[gid] = m;
}

// ---- phase 4: 5-tap col max -> NMS keep, 4 px/thread, ballot compaction -----
__global__ void nms_colcand_k(const float* __restrict__ cs, const float* __restrict__ rm,
                              float* __restrict__ cand_base, int* __restrict__ cand_cnt,
                              int total) {
    int g4 = blockIdx.x * 256 + threadIdx.x;
    int b = (blockIdx.x * 1024) / HWP;   // 1024 px/block divides HWP -> no straddle
    bool c[4] = {false, false, false, false};
    float4 v = make_float4(0.f, 0.f, 0.f, 0.f);
    int p = 0;
    if (g4 * 4 < total) {
        int qrow = g4 / (WW / 4);        // b*HH + y
        int y = qrow % HH;
        int xq = g4 % (WW / 4);
        p = y * WW + xq * 4;             // pixel index within image
        v = ((const float4*)cs)[g4];
        int y0 = y - 2 < 0 ? 0 : y - 2;
        int y1 = y + 2 > HH - 1 ? HH - 1 : y + 2;
        const float4* R = (const float4*)rm;
        int rb = b * HH;
        float4 nm = R[(rb + y0) * (WW / 4) + xq];
        for (int yy = y0 + 1; yy <= y1; ++yy) {
            float4 r = R[(rb + yy) * (WW / 4) + xq];
            nm.x = fmaxf(nm.x, r.x); nm.y = fmaxf(nm.y, r.y);
            nm.z = fmaxf(nm.z, r.z); nm.w = fmaxf(nm.w, r.w);
        }
        c[0] = (v.x > 0.f) && (v.x >= nm.x);
        c[1] = (v.y > 0.f) && (v.y >= nm.y);
        c[2] = (v.z > 0.f) && (v.z >= nm.z);
        c[3] = (v.w > 0.f) && (v.w >= nm.w);
    }
    unsigned long long m0 = __ballot(c[0]), m1 = __ballot(c[1]);
    unsigned long long m2 = __ballot(c[2]), m3 = __ballot(c[3]);
    int lane = threadIdx.x & 63;
    int w = threadIdx.x >> 6;
    unsigned long long lower = (1ULL << lane) - 1ULL;
    int t0 = __popcll(m0), t1 = __popcll(m1), t2 = __popcll(m2), t3 = __popcll(m3);
    int wtot = t0 + t1 + t2 + t3;
    int off[4];
    off[0] = __popcll(m0 & lower);
    off[1] = t0 + __popcll(m1 & lower);
    off[2] = t0 + t1 + __popcll(m2 & lower);
    off[3] = t0 + t1 + t2 + __popcll(m3 & lower);
    __shared__ int wbase[4];
    __shared__ int blockbase;
    if (lane == 0) wbase[w] = wtot;
    __syncthreads();
    if (threadIdx.x == 0) {
        int a0 = wbase[0], a1 = wbase[1], a2 = wbase[2], a3 = wbase[3];
        int tot = a0 + a1 + a2 + a3;
        wbase[0] = 0; wbase[1] = a0; wbase[2] = a0 + a1; wbase[3] = a0 + a1 + a2;
        blockbase = tot ? atomicAdd(&cand_cnt[b * CNT_STRIDE], tot) : 0;
    }
    __syncthreads();
    float vv[4] = {v.x, v.y, v.z, v.w};
    float* cv = cand_base + b * HWP;
    int* ci = (int*)(cand_base + b * HWP + CAP);
    for (int j = 0; j < 4; ++j) {
        if (c[j]) {
            int slot = blockbase + wbase[w] + off[j];
            if (slot < CAP) { cv[slot] = vv[j]; ci[slot] = p + j; }
        }
    }
}

// ---- phase 5: radix-select top-80 + peak params + tile binning --------------
__global__ void topk_bin_k(const float* __restrict__ cand_base, const int* __restrict__ cand_cnt,
                           const float* __restrict__ depth, float4* __restrict__ pk4g,
                           int* __restrict__ tcnt, int* __restrict__ tlist) {
    int b = blockIdx.x;
    int tid = threadIdx.x;  // 512 threads
    int n = cand_cnt[b * CNT_STRIDE];
    if (n > CAP) n = CAP;
    const float* cv = cand_base + b * HWP;
    const int* ci = (const int*)(cand_base + b * HWP + CAP);

    __shared__ int hist[256];
    __shared__ unsigned s_prefix;
    __shared__ int s_kth;
    __shared__ float sel_v[KTOP];
    __shared__ int sel_i[KTOP];
    __shared__ int s_ng, s_nt;
    __shared__ int tie_i[512];
    __shared__ float4 spk[KTOP];
    __shared__ float scut[KTOP];

    if (tid == 0) { s_prefix = 0; s_kth = KTOP; s_ng = 0; s_nt = 0; }
    if (tid < KTOP) { sel_v[tid] = 0.f; sel_i[tid] = -1; }
    __syncthreads();

    if (n > KTOP) {
        for (int shift = 24; shift >= 0; shift -= 8) {
            if (tid < 256) hist[tid] = 0;
            __syncthreads();
            unsigned pref = s_prefix;
            unsigned hmask = (shift == 24) ? 0u : (0xFFFFFFFFu << (shift + 8));
            for (int i = tid; i < n; i += 512) {
                unsigned u = __float_as_uint(cv[i]);
                if ((u & hmask) == (pref & hmask))
                    atomicAdd(&hist[(u >> shift) & 255], 1);
            }
            __syncthreads();
            if (tid < 64) {
                int h0 = hist[tid*4+0], h1 = hist[tid*4+1], h2 = hist[tid*4+2], h3 = hist[tid*4+3];
                int ls3 = h3, ls2 = h2 + ls3, ls1 = h1 + ls2, ls0 = h0 + ls1;
                int sum = ls0;
                for (int off = 1; off < 64; off <<= 1) {
                    int vv = __shfl_down(sum, off, 64);
                    if (tid + off < 64) sum += vv;
                }
                int excl = sum - ls0;
                int kth = s_kth;
                int SS0 = ls0 + excl, SS1 = ls1 + excl, SS2 = ls2 + excl, SS3 = ls3 + excl, SS4 = excl;
                unsigned pr = s_prefix;
                int bin = -1, rem = 0;
                if (SS0 >= kth && SS1 < kth) { bin = tid*4+0; rem = kth - SS1; }
                else if (SS1 >= kth && SS2 < kth) { bin = tid*4+1; rem = kth - SS2; }
                else if (SS2 >= kth && SS3 < kth) { bin = tid*4+2; rem = kth - SS3; }
                else if (SS3 >= kth && SS4 < kth) { bin = tid*4+3; rem = kth - SS4; }
                if (bin >= 0) { s_prefix = pr | ((unsigned)bin << shift); s_kth = rem; }
            }
            __syncthreads();
        }
        unsigned T = s_prefix;
        int need_eq = s_kth;
        for (int i = tid; i < n; i += 512) {
            unsigned u = __float_as_uint(cv[i]);
            if (u > T) {
                int s2 = atomicAdd(&s_ng, 1);
                if (s2 < KTOP) { sel_v[s2] = cv[i]; sel_i[s2] = ci[i]; }
            } else if (u == T) {
                int s2 = atomicAdd(&s_nt, 1);
                if (s2 < 512) tie_i[s2] = ci[i];
            }
        }
        __syncthreads();
        int G = s_ng; if (G > KTOP) G = KTOP;
        int nt = s_nt; if (nt > 512) nt = 512;
        for (int t = tid; t < nt; t += 512) {
            int mine = tie_i[t];
            int rank = 0;
            for (int j = 0; j < nt; ++j)
                if (tie_i[j] < mine) rank++;
            if (rank < need_eq && G + rank < KTOP) {
                sel_v[G + rank] = __uint_as_float(T);
                sel_i[G + rank] = mine;
            }
        }
        __syncthreads();
    } else {
        for (int i = tid; i < n; i += 512) { sel_v[i] = cv[i]; sel_i[i] = ci[i]; }
        __syncthreads();
    }

    if (tid < KTOP) {
        float val = sel_v[tid];
        int idx = sel_i[tid];
        float xk = 0.f, yk = 0.f, wv = 0.f, lv = -INFINITY, cut = -1.f;
        if (val > 0.f && idx >= 0) {
            yk = (float)(idx / WW);
            xk = (float)(idx % WW);
            float z = fmaxf(depth[b * HWP + idx], 1e-3f);
            float r = fminf(fmaxf(14.0f / z, 1.5f), 18.0f);
            float s2 = 0.6f * r;
            s2 = s2 * s2;
            wv = -LOG2E / (2.0f * s2 + 1e-6f);
            lv = log2f(val);
            cut = (lv + NLOG2TAU) / (-wv);
        }
        float4 pk = make_float4(lv, xk, yk, wv);
        spk[tid] = pk;
        scut[tid] = cut;
        pk4g[b * KTOP + tid] = pk;
    }
    __syncthreads();

    for (int t = tid; t < TPI; t += 512) {
        int ty = t / TPR, tx = t % TPR;
        float x0 = (float)(tx * TS), x1 = x0 + (TS - 1);
        float y0 = (float)(ty * TS), y1 = y0 + (TS - 1);
        int cnum = 0;
        int base = (b * TPI + t) * KTOP;
        for (int k = 0; k < KTOP; ++k) {
            float4 pk = spk[k];
            float cx = fminf(fmaxf(pk.y, x0), x1);
            float cy = fminf(fmaxf(pk.z, y0), y1);
            float dx = pk.y - cx, dy = pk.z - cy;
            float d2 = dx * dx + dy * dy;
            if (d2 <= scut[k]) tlist[base + cnum++] = k;
        }
        tcnt[b * TPI + t] = cnum;
    }
}

// ---- phase 6: gaussian max over tile's peak list; minmax -> scratch ---------
__global__ void gauss_tiled_k(const float4* __restrict__ pk4g, const int* __restrict__ tcnt,
                              const int* __restrict__ tlist, float* __restrict__ gauss,
                              float2* __restrict__ gmm) {
    int tb = blockIdx.x;
    int b = tb / TPI;
    int t = tb % TPI;
    int ty = t / TPR, tx = t % TPR;
    int ly = threadIdx.x / TS, lx = threadIdx.x % TS;
    int y = ty * TS + ly, x = tx * TS + lx;
    __shared__ float4 spk[KTOP];
    int cnt = tcnt[tb];
    if (threadIdx.x < cnt)
        spk[threadIdx.x] = pk4g[b * KTOP + tlist[tb * KTOP + threadIdx.x]];
    __syncthreads();
    float fx = (float)x, fy = (float)y;
    float m = 0.f;
    for (int i = 0; i < cnt; ++i) {
        float4 pk = spk[i];
        float dx = fx - pk.y, dy = fy - pk.z;
        float d2 = fmaf(dx, dx, dy * dy);
        m = fmaxf(m, __builtin_amdgcn_exp2f(fmaf(d2, pk.w, pk.x)));
    }
    gauss[b * HWP + y * WW + x] = m;
    float tmn = m, tmx = m;
    wave_minmax(tmn, tmx);
    __shared__ float wmn[4], wmx[4];
    int w = threadIdx.x >> 6;
    if ((threadIdx.x & 63) == 0) { wmn[w] = tmn; wmx[w] = tmx; }
    __syncthreads();
    if (threadIdx.x == 0) {
        gmm[tb] = make_float2(fminf(fminf(wmn[0], wmn[1]), fminf(wmn[2], wmn[3])),
                              fmaxf(fmaxf(wmx[0], wmx[1]), fmaxf(wmx[2], wmx[3])));
    }
}

// ---- phase 7: final norm01, 4 px/thread; gauss-minmax reduced in-block ------
__global__ void norm_k(const float* __restrict__ gauss, const float2* __restrict__ gmm,
                       float* __restrict__ out, int total) {
    int g4 = blockIdx.x * 256 + threadIdx.x;
    int b = (blockIdx.x * 1024) / HWP;
    // reduce this batch's 400 per-tile minmax pairs
    float tmn = INFINITY, tmx = 0.f;
    {
        int t = threadIdx.x;
        if (t < TPI) { float2 e = gmm[b * TPI + t]; tmn = e.x; tmx = e.y; }
        int t2 = t + 256;
        if (t2 < TPI) { float2 e = gmm[b * TPI + t2]; tmn = fminf(tmn, e.x); tmx = fmaxf(tmx, e.y); }
    }
    wave_minmax(tmn, tmx);
    __shared__ float wmn[4], wmx[4];
    __shared__ float bmn, binv;
    int w = threadIdx.x >> 6;
    if ((threadIdx.x & 63) == 0) { wmn[w] = tmn; wmx[w] = tmx; }
    __syncthreads();
    if (threadIdx.x == 0) {
        float mn = fminf(fminf(wmn[0], wmn[1]), fminf(wmn[2], wmn[3]));
        float mx = fmaxf(fmaxf(wmx[0], wmx[1]), fmaxf(wmx[2], wmx[3]));
        bmn = mn;
        binv = 1.0f / (mx - mn + 1e-6f);
    }
    __syncthreads();
    if (g4 * 4 >= total) return;
    float4 g = ((const float4*)gauss)[g4];
    ((float4*)out)[g4] = make_float4((g.x - bmn) * binv, (g.y - bmn) * binv,
                                     (g.z - bmn) * binv, (g.w - bmn) * binv);
}

extern "C" void kernel_launch(void* const* d_in, const int* in_sizes, int n_in,
                              void* d_out, int out_size, void* d_ws, size_t ws_size,
                              hipStream_t stream) {
    const float* score = (const float*)d_in[0];
    const float* depth = (const float*)d_in[1];
    float* out = (float*)d_out;
    int total = in_sizes[0];       // B * H * W
    int B_ = total / HWP;          // 8

    // workspace (floats), with reuse:
    //  buf0: rs_s -> cs -> gauss
    //  buf1: rs_o -> rm -> {tcnt[B*TPI] | tlist[B*TPI*KTOP] | gmm[B*TPI] float2}
    //  buf2: prod -> {cand_val[0:CAP] | cand_idx[CAP:2*CAP]} per batch
    //  small: peaks (float4, 16B-aligned) | cand_cnt | pmm
    float* buf0 = (float*)d_ws;
    float* buf1 = buf0 + total;
    float* buf2 = buf1 + total;
    char* small = (char*)(buf2 + total);
    float4* pk4 = (float4*)small;
    int* cand_cnt = (int*)(small + B_ * KTOP * sizeof(float4));
    float2* pmm = (float2*)(small + B_ * KTOP * sizeof(float4) + B_ * CNT_STRIDE * sizeof(int));
    int* tcnt = (int*)buf1;
    int* tlist = tcnt + B_ * TPI;
    float2* gmm = (float2*)(tlist + B_ * TPI * KTOP);

    int nb4 = (total / 4 + 255) / 256;     // 800

    row_pool_k<<<nb4, 256, 0, stream>>>(score, buf0, buf1, total, cand_cnt, B_);
    col_prod_k<<<nb4, 256, 0, stream>>>(buf0, buf1, buf2, pmm, total);
    cs_rowmax_k<<<B_ * HH, WW, 0, stream>>>(score, buf2, pmm, buf0, buf1);       // buf0=cs, buf1=rm
    nms_colcand_k<<<nb4, 256, 0, stream>>>(buf0, buf1, buf2, cand_cnt, total);   // buf2=cand pack
    topk_bin_k<<<B_, 512, 0, stream>>>(buf2, cand_cnt, depth, pk4, tcnt, tlist);
    gauss_tiled_k<<<B_ * TPI, 256, 0, stream>>>(pk4, tcnt, tlist, buf0, gmm);    // buf0=gauss
    norm_k<<<nb4, 256, 0, stream>>>(buf0, gmm, out, total);
}

// Round 6
// 37.888 us; speedup vs baseline: 17.5853x; 1.6244x over previous
//
#include <hip/hip_runtime.h>
#include <math.h>

#define HH 320
#define WW 320
#define HWP (HH * WW)       // pixels per batch image
#define KTOP 80
#define CNT_STRIDE 64       // pad per-batch counters to separate 256B lines
#define CAP (HWP / 2)       // max candidates kept per batch (val+idx pack one buffer)
#define TS 16               // gauss tile size
#define TPR (WW / TS)       // 20 gauss tiles per row
#define TPI (TPR * (HH / TS))  // 400 gauss tiles per image
#define TW 32               // pool/nms tile width
#define TH 64               // pool/nms tile height
#define NTPRX (WW / TW)     // 10 tiles per row
#define NTPI (NTPRX * (HH / TH))  // 50 tiles per image
#define LOG2E 1.4426950408889634f
#define NLOG2TAU 19.931568569324174f   // -log2(1e-6)

__device__ __forceinline__ void wave_minmax(float& mn, float& mx) {
    for (int off = 32; off > 0; off >>= 1) {
        mn = fminf(mn, __shfl_xor(mn, off, 64));
        mx = fmaxf(mx, __shfl_xor(mx, off, 64));
    }
}

// ---- K1: fused 9x9 avg pools -> prod, per-block minmax -> pmm ---------------
__global__ void pool_fused_k(const float* __restrict__ score, float* __restrict__ prod,
                             float2* __restrict__ pmm, int* __restrict__ cand_cnt, int B_) {
    int tid = threadIdx.x;
    if (blockIdx.x == 0)
        for (int t = tid; t < B_ * CNT_STRIDE; t += 256) cand_cnt[t] = 0;
    int blk = blockIdx.x;
    int b = blk / NTPI, t = blk % NTPI;
    int ty0 = (t / NTPRX) * TH, tx0 = (t % NTPRX) * TW;
    __shared__ float rss[TH + 8][TW + 4];   // [72][36], row sums (score)
    __shared__ float rso[TH + 8][TW + 4];   // [72][36], row sums (occ)
    const float4* img4 = (const float4*)(score + b * HWP);
    // phase A: 9-tap row sums for 72 rows x 8 quads (zero-pad OOB)
    for (int i = tid; i < (TH + 8) * (TW / 4); i += 256) {
        int r = i / (TW / 4), q = i % (TW / 4);
        int gy = ty0 - 4 + r;
        float o0=0,o1=0,o2=0,o3=0,p0=0,p1=0,p2=0,p3=0;
        if (gy >= 0 && gy < HH) {
            const float4* row4 = img4 + gy * (WW / 4);
            int gq = tx0 / 4 + q;
            float4 a = (gq > 0) ? row4[gq - 1] : make_float4(0,0,0,0);
            float4 bb = row4[gq];
            float4 c = (gq < WW / 4 - 1) ? row4[gq + 1] : make_float4(0,0,0,0);
            float w0=a.x,w1=a.y,w2=a.z,w3=a.w,w4=bb.x,w5=bb.y,w6=bb.z,w7=bb.w,w8=c.x,w9=c.y,w10=c.z,w11=c.w;
            float s = w0+w1+w2+w3+w4+w5+w6+w7+w8;
            o0=s; s+=w9-w0; o1=s; s+=w10-w1; o2=s; s+=w11-w2; o3=s;
            float c0=(w0>0.2f)?1.f:0.f, c1=(w1>0.2f)?1.f:0.f, c2=(w2>0.2f)?1.f:0.f, c3=(w3>0.2f)?1.f:0.f;
            float c4=(w4>0.2f)?1.f:0.f, c5=(w5>0.2f)?1.f:0.f, c6=(w6>0.2f)?1.f:0.f, c7=(w7>0.2f)?1.f:0.f;
            float c8=(w8>0.2f)?1.f:0.f, c9=(w9>0.2f)?1.f:0.f, c10=(w10>0.2f)?1.f:0.f, c11=(w11>0.2f)?1.f:0.f;
            float u = c0+c1+c2+c3+c4+c5+c6+c7+c8;
            p0=u; u+=c9-c0; p1=u; u+=c10-c1; p2=u; u+=c11-c2; p3=u;
        }
        *(float4*)&rss[r][q * 4] = make_float4(o0,o1,o2,o3);
        *(float4*)&rso[r][q * 4] = make_float4(p0,p1,p2,p3);
    }
    __syncthreads();
    // phase B: 9-tap column sums -> prod + minmax
    float tmn = INFINITY, tmx = 0.f;
    const float inv81 = 1.0f / 81.0f;
    float4* pr4 = (float4*)(prod + b * HWP);
    for (int i = tid; i < TH * (TW / 4); i += 256) {
        int r = i / (TW / 4), q = i % (TW / 4);
        float sx=0,sy=0,sz=0,sw=0, ox=0,oy=0,oz=0,ow=0;
#pragma unroll
        for (int j = 0; j < 9; ++j) {
            float4 s = *(float4*)&rss[r + j][q * 4];
            float4 o = *(float4*)&rso[r + j][q * 4];
            sx+=s.x; sy+=s.y; sz+=s.z; sw+=s.w;
            ox+=o.x; oy+=o.y; oz+=o.z; ow+=o.w;
        }
        float px=(ox*inv81)*(sx*inv81), py=(oy*inv81)*(sy*inv81);
        float pz=(oz*inv81)*(sz*inv81), pw=(ow*inv81)*(sw*inv81);
        pr4[(ty0 + r) * (WW / 4) + tx0 / 4 + q] = make_float4(px,py,pz,pw);
        tmn = fminf(tmn, fminf(fminf(px,py), fminf(pz,pw)));
        tmx = fmaxf(tmx, fmaxf(fmaxf(px,py), fmaxf(pz,pw)));
    }
    wave_minmax(tmn, tmx);
    __shared__ float wmn[4], wmx[4];
    int w = tid >> 6;
    if ((tid & 63) == 0) { wmn[w] = tmn; wmx[w] = tmx; }
    __syncthreads();
    if (tid == 0)
        pmm[blk] = make_float2(fminf(fminf(wmn[0],wmn[1]), fminf(wmn[2],wmn[3])),
                               fmaxf(fmaxf(wmx[0],wmx[1]), fmaxf(wmx[2],wmx[3])));
}

// ---- K2: compact_score + 5x5 NMS (separable, in LDS) + compaction -----------
__global__ void cs_nms_k(const float* __restrict__ score, const float* __restrict__ prod,
                         const float2* __restrict__ pmm, float* __restrict__ cand_base,
                         int* __restrict__ cand_cnt) {
    int tid = threadIdx.x;
    int blk = blockIdx.x;
    int b = blk / NTPI, t = blk % NTPI;
    int ty0 = (t / NTPRX) * TH, tx0 = (t % NTPRX) * TW;
    // reduce this batch's NTPI pmm pairs (wave 0 does the work)
    float tmn = INFINITY, tmx = 0.f;
    if (tid < NTPI) { float2 e = pmm[b * NTPI + tid]; tmn = e.x; tmx = e.y; }
    wave_minmax(tmn, tmx);
    __shared__ float s_mn, s_inv;
    if (tid == 0) { s_mn = tmn; s_inv = 1.0f / (tmx - tmn + 1e-6f); }
    __shared__ float cs[TH + 4][TW + 8 + 4];   // [68][44], col 0 <-> gx = tx0-4
    __shared__ float rm[TH + 4][TW + 4];       // [68][36], 5-tap row max
    __syncthreads();
    float mn = s_mn, inv = s_inv;
    const float4* sc4 = (const float4*)(score + b * HWP);
    const float4* pr4 = (const float4*)(prod + b * HWP);
    // phase A: cs over rows ty0-2..+65, 10 col quads (zero-pad OOB)
    for (int i = tid; i < (TH + 4) * 10; i += 256) {
        int r = i / 10, q = i % 10;
        int gy = ty0 - 2 + r;
        int gq = tx0 / 4 - 1 + q;
        float4 c4 = make_float4(0,0,0,0);
        if (gy >= 0 && gy < HH && gq >= 0 && gq < WW / 4) {
            float4 s4 = sc4[gy * (WW / 4) + gq];
            float4 p4 = pr4[gy * (WW / 4) + gq];
            c4.x = s4.x * ((p4.x - mn) * inv); c4.y = s4.y * ((p4.y - mn) * inv);
            c4.z = s4.z * ((p4.z - mn) * inv); c4.w = s4.w * ((p4.w - mn) * inv);
        }
        *(float4*)&cs[r][q * 4] = c4;
    }
    __syncthreads();
    // phase B: rm[r][x] = max cs[r][x+2 .. x+6]  (px col x <-> cs col x+4)
    for (int i = tid; i < (TH + 4) * (TW / 4); i += 256) {
        int r = i / (TW / 4), x = (i % (TW / 4)) * 4;
        float c0=cs[r][x+2], c1=cs[r][x+3], c2=cs[r][x+4], c3=cs[r][x+5];
        float c4v=cs[r][x+6], c5=cs[r][x+7], c6=cs[r][x+8], c7=cs[r][x+9];
        float m01=fmaxf(c0,c1), m23=fmaxf(c2,c3), m45=fmaxf(c4v,c5), m67=fmaxf(c6,c7);
        float r0 = fmaxf(fmaxf(m01, m23), c4v);
        float r1 = fmaxf(fmaxf(c1, m23), m45);
        float r2 = fmaxf(fmaxf(m23, m45), c6);
        float r3 = fmaxf(fmaxf(c3, m45), m67);
        *(float4*)&rm[r][x] = make_float4(r0,r1,r2,r3);
    }
    __syncthreads();
    // phase C: NMS decision, 2 quads/thread (512 quads = 2*256 exactly)
    bool cd[8]; float vv[8]; int pb[2]; int offs[8];
#pragma unroll
    for (int qq = 0; qq < 2; ++qq) {
        int quad = qq * 256 + tid;
        int r = quad >> 3, x = (quad & 7) * 4;
        float4 v = *(float4*)&cs[r + 2][x + 4];
        float4 nm = *(float4*)&rm[r][x];
#pragma unroll
        for (int k = 1; k <= 4; ++k) {
            float4 rr = *(float4*)&rm[r + k][x];
            nm.x=fmaxf(nm.x,rr.x); nm.y=fmaxf(nm.y,rr.y);
            nm.z=fmaxf(nm.z,rr.z); nm.w=fmaxf(nm.w,rr.w);
        }
        pb[qq] = (ty0 + r) * WW + tx0 + x;
        cd[qq*4+0] = v.x > 0.f && v.x >= nm.x; vv[qq*4+0] = v.x;
        cd[qq*4+1] = v.y > 0.f && v.y >= nm.y; vv[qq*4+1] = v.y;
        cd[qq*4+2] = v.z > 0.f && v.z >= nm.z; vv[qq*4+2] = v.z;
        cd[qq*4+3] = v.w > 0.f && v.w >= nm.w; vv[qq*4+3] = v.w;
    }
    int lane = tid & 63, w = tid >> 6;
    unsigned long long lower = (1ULL << lane) - 1ULL;
    int wave_run = 0;
#pragma unroll
    for (int j = 0; j < 8; ++j) {
        unsigned long long m = __ballot(cd[j]);
        offs[j] = wave_run + __popcll(m & lower);
        wave_run += __popcll(m);
    }
    __shared__ int wbase[4];
    __shared__ int blockbase;
    if (lane == 0) wbase[w] = wave_run;
    __syncthreads();
    if (tid == 0) {
        int a0=wbase[0], a1=wbase[1], a2=wbase[2], a3=wbase[3];
        int tot = a0+a1+a2+a3;
        wbase[0]=0; wbase[1]=a0; wbase[2]=a0+a1; wbase[3]=a0+a1+a2;
        blockbase = tot ? atomicAdd(&cand_cnt[b * CNT_STRIDE], tot) : 0;
    }
    __syncthreads();
    float* cv = cand_base + b * HWP;
    int* ci = (int*)(cand_base + b * HWP + CAP);
    int bb2 = blockbase + wbase[w];
#pragma unroll
    for (int j = 0; j < 8; ++j) {
        if (cd[j]) {
            int slot = bb2 + offs[j];
            if (slot < CAP) { cv[slot] = vv[j]; ci[slot] = pb[j >> 2] + (j & 3); }
        }
    }
}

// ---- K3: radix-select top-80 per batch + peak params ------------------------
__global__ void topk_k(const float* __restrict__ cand_base, const int* __restrict__ cand_cnt,
                       const float* __restrict__ depth, float4* __restrict__ pk4g) {
    int b = blockIdx.x;
    int tid = threadIdx.x;  // 1024 threads
    int n = cand_cnt[b * CNT_STRIDE];
    if (n > CAP) n = CAP;
    const float* cv = cand_base + b * HWP;
    const int* ci = (const int*)(cand_base + b * HWP + CAP);

    __shared__ int hist[256];
    __shared__ unsigned s_prefix;
    __shared__ int s_kth;
    __shared__ float sel_v[KTOP];
    __shared__ int sel_i[KTOP];
    __shared__ int s_ng, s_nt;
    __shared__ int tie_i[512];

    if (tid == 0) { s_prefix = 0; s_kth = KTOP; s_ng = 0; s_nt = 0; }
    if (tid < KTOP) { sel_v[tid] = 0.f; sel_i[tid] = -1; }
    __syncthreads();

    if (n > KTOP) {
        for (int shift = 24; shift >= 0; shift -= 8) {
            if (tid < 256) hist[tid] = 0;
            __syncthreads();
            unsigned pref = s_prefix;
            unsigned hmask = (shift == 24) ? 0u : (0xFFFFFFFFu << (shift + 8));
            for (int i = tid; i < n; i += 1024) {
                unsigned u = __float_as_uint(cv[i]);
                if ((u & hmask) == (pref & hmask))
                    atomicAdd(&hist[(u >> shift) & 255], 1);
            }
            __syncthreads();
            if (tid < 64) {   // single-wave suffix scan, lane L owns bins 4L..4L+3
                int h0 = hist[tid*4+0], h1 = hist[tid*4+1], h2 = hist[tid*4+2], h3 = hist[tid*4+3];
                int ls3 = h3, ls2 = h2 + ls3, ls1 = h1 + ls2, ls0 = h0 + ls1;
                int sum = ls0;
                for (int off = 1; off < 64; off <<= 1) {
                    int vv2 = __shfl_down(sum, off, 64);
                    if (tid + off < 64) sum += vv2;
                }
                int excl = sum - ls0;
                int kth = s_kth;
                int SS0=ls0+excl, SS1=ls1+excl, SS2=ls2+excl, SS3=ls3+excl, SS4=excl;
                unsigned pr = s_prefix;
                int bin = -1, rem = 0;
                if (SS0 >= kth && SS1 < kth) { bin = tid*4+0; rem = kth - SS1; }
                else if (SS1 >= kth && SS2 < kth) { bin = tid*4+1; rem = kth - SS2; }
                else if (SS2 >= kth && SS3 < kth) { bin = tid*4+2; rem = kth - SS3; }
                else if (SS3 >= kth && SS4 < kth) { bin = tid*4+3; rem = kth - SS4; }
                if (bin >= 0) { s_prefix = pr | ((unsigned)bin << shift); s_kth = rem; }
            }
            __syncthreads();
        }
        unsigned T = s_prefix;
        int need_eq = s_kth;
        for (int i = tid; i < n; i += 1024) {
            unsigned u = __float_as_uint(cv[i]);
            if (u > T) {
                int s2 = atomicAdd(&s_ng, 1);
                if (s2 < KTOP) { sel_v[s2] = cv[i]; sel_i[s2] = ci[i]; }
            } else if (u == T) {
                int s2 = atomicAdd(&s_nt, 1);
                if (s2 < 512) tie_i[s2] = ci[i];
            }
        }
        __syncthreads();
        int G = s_ng; if (G > KTOP) G = KTOP;
        int nt = s_nt; if (nt > 512) nt = 512;
        for (int t = tid; t < nt; t += 1024) {
            int mine = tie_i[t];
            int rank = 0;
            for (int j = 0; j < nt; ++j)
                if (tie_i[j] < mine) rank++;   // pixel indices distinct
            if (rank < need_eq && G + rank < KTOP) {
                sel_v[G + rank] = __uint_as_float(T);
                sel_i[G + rank] = mine;
            }
        }
        __syncthreads();
    } else {
        for (int i = tid; i < n; i += 1024) { sel_v[i] = cv[i]; sel_i[i] = ci[i]; }
        __syncthreads();
    }

    if (tid < KTOP) {
        float val = sel_v[tid];
        int idx = sel_i[tid];
        float xk = 0.f, yk = 0.f, wv = -1.f, lv = -INFINITY;
        if (val > 0.f && idx >= 0) {
            yk = (float)(idx / WW);
            xk = (float)(idx % WW);
            float z = fmaxf(depth[b * HWP + idx], 1e-3f);
            float r = fminf(fmaxf(14.0f / z, 1.5f), 18.0f);
            float s2 = 0.6f * r;
            s2 = s2 * s2;
            wv = -LOG2E / (2.0f * s2 + 1e-6f);
            lv = log2f(val);
        }
        pk4g[b * KTOP + tid] = make_float4(lv, xk, yk, wv);
    }
}

// ---- K4: per-tile peak cull (in-block) + gaussian max; minmax -> gmm --------
__global__ void gauss_tiled_k(const float4* __restrict__ pk4g, float* __restrict__ gauss,
                              float2* __restrict__ gmm) {
    int tb = blockIdx.x, tid = threadIdx.x;
    int b = tb / TPI, t = tb % TPI;
    int ty = t / TPR, tx = t % TPR;
    __shared__ float4 spk[KTOP];
    __shared__ int s_c0, s_cnt;
    bool keep = false;
    float4 pk;
    if (tid < KTOP) {
        pk = pk4g[b * KTOP + tid];
        float cut = (pk.x + NLOG2TAU) / (-pk.w);   // invalid: (-inf+c)/1 = -inf -> drop
        float x0 = (float)(tx * TS), x1 = x0 + (TS - 1);
        float y0 = (float)(ty * TS), y1 = y0 + (TS - 1);
        float cx = fminf(fmaxf(pk.y, x0), x1);
        float cy = fminf(fmaxf(pk.z, y0), y1);
        float dx = pk.y - cx, dy = pk.z - cy;
        keep = (dx * dx + dy * dy) <= cut;
    }
    int lane = tid & 63, w = tid >> 6;
    unsigned long long m = __ballot(keep);
    if (w == 0 && lane == 0) s_c0 = __popcll(m);
    __syncthreads();
    int base = (w == 0) ? 0 : s_c0;
    if (keep) spk[base + __popcll(m & ((1ULL << lane) - 1ULL))] = pk;
    if (w == 1 && lane == 0) s_cnt = s_c0 + __popcll(m);
    __syncthreads();
    int cnt = s_cnt;
    int ly = tid / TS, lx = tid % TS;
    int y = ty * TS + ly, x = tx * TS + lx;
    float fx = (float)x, fy = (float)y;
    float mval = 0.f;
    for (int i = 0; i < cnt; ++i) {
        float4 p = spk[i];
        float dx = fx - p.y, dy = fy - p.z;
        mval = fmaxf(mval, __builtin_amdgcn_exp2f(fmaf(fmaf(dx, dx, dy * dy), p.w, p.x)));
    }
    gauss[b * HWP + y * WW + x] = mval;
    float tmn = mval, tmx = mval;
    wave_minmax(tmn, tmx);
    __shared__ float wmn[4], wmx[4];
    if (lane == 0) { wmn[w] = tmn; wmx[w] = tmx; }
    __syncthreads();
    if (tid == 0)
        gmm[tb] = make_float2(fminf(fminf(wmn[0],wmn[1]), fminf(wmn[2],wmn[3])),
                              fmaxf(fmaxf(wmx[0],wmx[1]), fmaxf(wmx[2],wmx[3])));
}

// ---- K5: final norm01, 4 px/thread; gauss-minmax reduced in-block -----------
__global__ void norm_k(const float* __restrict__ gauss, const float2* __restrict__ gmm,
                       float* __restrict__ out, int total) {
    int g4 = blockIdx.x * 256 + threadIdx.x;
    int b = (blockIdx.x * 1024) / HWP;
    float tmn = INFINITY, tmx = 0.f;
    {
        int t = threadIdx.x;
        if (t < TPI) { float2 e = gmm[b * TPI + t]; tmn = e.x; tmx = e.y; }
        int t2 = t + 256;
        if (t2 < TPI) { float2 e = gmm[b * TPI + t2]; tmn = fminf(tmn, e.x); tmx = fmaxf(tmx, e.y); }
    }
    wave_minmax(tmn, tmx);
    __shared__ float wmn[4], wmx[4];
    __shared__ float bmn, binv;
    int w = threadIdx.x >> 6;
    if ((threadIdx.x & 63) == 0) { wmn[w] = tmn; wmx[w] = tmx; }
    __syncthreads();
    if (threadIdx.x == 0) {
        float mn = fminf(fminf(wmn[0],wmn[1]), fminf(wmn[2],wmn[3]));
        float mx = fmaxf(fmaxf(wmx[0],wmx[1]), fmaxf(wmx[2],wmx[3]));
        bmn = mn;
        binv = 1.0f / (mx - mn + 1e-6f);
    }
    __syncthreads();
    if (g4 * 4 >= total) return;
    float4 g = ((const float4*)gauss)[g4];
    ((float4*)out)[g4] = make_float4((g.x - bmn) * binv, (g.y - bmn) * binv,
                                     (g.z - bmn) * binv, (g.w - bmn) * binv);
}

extern "C" void kernel_launch(void* const* d_in, const int* in_sizes, int n_in,
                              void* d_out, int out_size, void* d_ws, size_t ws_size,
                              hipStream_t stream) {
    const float* score = (const float*)d_in[0];
    const float* depth = (const float*)d_in[1];
    float* out = (float*)d_out;
    int total = in_sizes[0];       // B * H * W
    int B_ = total / HWP;          // 8

    // workspace:
    //  buf0: gauss
    //  buf1: prod
    //  buf2: {cand_val[0:CAP] | cand_idx[CAP:2*CAP]} per batch
    //  small: pk4 | cand_cnt | pmm | gmm
    float* buf0 = (float*)d_ws;
    float* buf1 = buf0 + total;
    float* buf2 = buf1 + total;
    char* small = (char*)(buf2 + total);
    float4* pk4 = (float4*)small;
    int* cand_cnt = (int*)(small + B_ * KTOP * sizeof(float4));
    float2* pmm = (float2*)((char*)cand_cnt + B_ * CNT_STRIDE * sizeof(int));
    float2* gmm = pmm + B_ * NTPI;

    int nb4 = (total / 4 + 255) / 256;     // 800

    pool_fused_k<<<B_ * NTPI, 256, 0, stream>>>(score, buf1, pmm, cand_cnt, B_);
    cs_nms_k<<<B_ * NTPI, 256, 0, stream>>>(score, buf1, pmm, buf2, cand_cnt);
    topk_k<<<B_, 1024, 0, stream>>>(buf2, cand_cnt, depth, pk4);
    gauss_tiled_k<<<B_ * TPI, 256, 0, stream>>>(pk4, buf0, gmm);
    norm_k<<<nb4, 256, 0, stream>>>(buf0, gmm, out, total);
}